// Round 7
// baseline (527.188 us; speedup 1.0000x reference)
//
#include <hip/hip_runtime.h>
#include <hip/hip_bf16.h>

#define N_NODES 100000
#define N_EDGES 600000
#define N_REL   3
#define D_INF   256
#define D_OUTF  128

#define SCAN_TOTAL (3 * N_NODES)                 // 300000
#define SCAN_ELEMS 1024                          // elems per block
#define SCAN_NBLK  ((SCAN_TOTAL + SCAN_ELEMS - 1) / SCAN_ELEMS)  // 293

typedef __attribute__((ext_vector_type(8))) short          bf16x8;
typedef __attribute__((ext_vector_type(8))) unsigned short ushort8;
typedef __attribute__((ext_vector_type(4))) float          f32x4;

// row stride (in bf16 elems) for LDS tiles: 72*2=144B -> 16B-aligned, and
// 16 rows spread over banks with only 2-way aliasing (free per m136)
#define LPAD 72

__device__ __forceinline__ unsigned short bf16_rne(float v) {
    unsigned int b = __float_as_uint(v);
    b += 0x7FFFu + ((b >> 16) & 1u);
    return (unsigned short)(b >> 16);
}

// ---------------------------------------------------------------------------
// K0: W [256][128] f32  ->  Wt_{hi,lo} [128 cols][256 k] bf16  (per W)
// ---------------------------------------------------------------------------
__global__ __launch_bounds__(128) void wt_prep(
    const float* __restrict__ Wl, const float* __restrict__ Wr,
    unsigned short* __restrict__ wt)
{
    const int k = blockIdx.x;      // 0..255
    const int w = blockIdx.y;      // 0,1
    const int n = threadIdx.x;     // 0..127
    const float v = (w ? Wr : Wl)[(size_t)k * D_OUTF + n];
    const unsigned short h = bf16_rne(v);
    const float fhi = __uint_as_float(((unsigned int)h) << 16);
    const unsigned short g = bf16_rne(v - fhi);
    const size_t base = (size_t)w * 2 * 128 * 256;
    wt[base + (size_t)n * 256 + k]          = h;
    wt[base + 32768 + (size_t)n * 256 + k]  = g;
}

// ---------------------------------------------------------------------------
// K1: projection GEMM via split-bf16 MFMA (C = xhi*Whi + xhi*Wlo + xlo*Whi)
// ---------------------------------------------------------------------------
__global__ __launch_bounds__(256) void proj_mfma(
    const float* __restrict__ x, const unsigned short* __restrict__ wt,
    const float* __restrict__ bl, const float* __restrict__ br,
    float* __restrict__ lbuf, float* __restrict__ rbuf)
{
    __shared__ unsigned short xs[2][64][LPAD];    // x tile   hi/lo
    __shared__ unsigned short ws2[2][128][LPAD];  // W^T tile hi/lo

    const int tid  = threadIdx.x;
    const int nb   = blockIdx.x * 64;
    const int w    = blockIdx.y;
    const unsigned short* wtw = wt + (size_t)w * 2 * 128 * 256;
    const float* bias = w ? br : bl;
    float*       obuf = w ? rbuf : lbuf;

    const int lane = tid & 63;
    const int wv   = tid >> 6;      // wave 0..3
    const int rowf = lane & 15;
    const int kgrp = lane >> 4;     // 0..3

    f32x4 acc[8];
#pragma unroll
    for (int cf = 0; cf < 8; ++cf) acc[cf] = (f32x4){0.f, 0.f, 0.f, 0.f};

    float bv[8];
#pragma unroll
    for (int cf = 0; cf < 8; ++cf) bv[cf] = bias[cf * 16 + rowf];

    for (int kb = 0; kb < D_INF; kb += 64) {
        __syncthreads();
        // ---- stage x tile: thread t -> row t>>2, 16 k's at (t&3)*16
        {
            const int r   = tid >> 2;
            const int seg = tid & 3;
            int rowg = nb + r; if (rowg >= N_NODES) rowg = N_NODES - 1;
            const float* src = x + (size_t)rowg * D_INF + kb + seg * 16;
#pragma unroll
            for (int q2 = 0; q2 < 2; ++q2) {
                const float4 v0 = *reinterpret_cast<const float4*>(src + q2 * 8);
                const float4 v1 = *reinterpret_cast<const float4*>(src + q2 * 8 + 4);
                const float vv[8] = {v0.x, v0.y, v0.z, v0.w, v1.x, v1.y, v1.z, v1.w};
                ushort8 hv, gv;
#pragma unroll
                for (int q = 0; q < 8; ++q) {
                    const unsigned short h = bf16_rne(vv[q]);
                    hv[q] = h;
                    const float fhi = __uint_as_float(((unsigned int)h) << 16);
                    gv[q] = bf16_rne(vv[q] - fhi);
                }
                *reinterpret_cast<ushort8*>(&xs[0][r][seg * 16 + q2 * 8]) = hv;
                *reinterpret_cast<ushort8*>(&xs[1][r][seg * 16 + q2 * 8]) = gv;
            }
        }
        // ---- stage W^T tile: thread t -> col n=t>>1, 32 k's at (t&1)*32
        {
            const int n    = tid >> 1;
            const int half = tid & 1;
            const uint4* sh = reinterpret_cast<const uint4*>(wtw + (size_t)n * 256 + kb + half * 32);
            const uint4* sl = reinterpret_cast<const uint4*>(wtw + 32768 + (size_t)n * 256 + kb + half * 32);
            uint4* dh = reinterpret_cast<uint4*>(&ws2[0][n][half * 32]);
            uint4* dl = reinterpret_cast<uint4*>(&ws2[1][n][half * 32]);
#pragma unroll
            for (int q = 0; q < 4; ++q) { dh[q] = sh[q]; dl[q] = sl[q]; }
        }
        __syncthreads();

        // ---- MFMA over the 2 k32-steps of this BK
#pragma unroll
        for (int kk = 0; kk < 2; ++kk) {
            const int ko = kk * 32 + kgrp * 8;
            const bf16x8 ahi = *reinterpret_cast<const bf16x8*>(&xs[0][wv * 16 + rowf][ko]);
            const bf16x8 alo = *reinterpret_cast<const bf16x8*>(&xs[1][wv * 16 + rowf][ko]);
#pragma unroll
            for (int cf = 0; cf < 8; ++cf) {
                const bf16x8 bhi = *reinterpret_cast<const bf16x8*>(&ws2[0][cf * 16 + rowf][ko]);
                const bf16x8 blo = *reinterpret_cast<const bf16x8*>(&ws2[1][cf * 16 + rowf][ko]);
                acc[cf] = __builtin_amdgcn_mfma_f32_16x16x32_bf16(ahi, bhi, acc[cf], 0, 0, 0);
                acc[cf] = __builtin_amdgcn_mfma_f32_16x16x32_bf16(ahi, blo, acc[cf], 0, 0, 0);
                acc[cf] = __builtin_amdgcn_mfma_f32_16x16x32_bf16(alo, bhi, acc[cf], 0, 0, 0);
            }
        }
    }

    // ---- epilogue: bias + relu + store (C layout: row=kgrp*4+j, col=rowf)
#pragma unroll
    for (int cf = 0; cf < 8; ++cf) {
#pragma unroll
        for (int j = 0; j < 4; ++j) {
            const int node = nb + wv * 16 + kgrp * 4 + j;
            if (node < N_NODES)
                obuf[(size_t)node * D_OUTF + cf * 16 + rowf] =
                    fmaxf(acc[cf][j] + bv[cf], 0.f);
        }
    }
}

// ---------------------------------------------------------------------------
// K2: per-node attention scalars
// ---------------------------------------------------------------------------
__global__ __launch_bounds__(256) void alar_kernel(
    const float* __restrict__ lbuf, const float* __restrict__ rbuf,
    const float* __restrict__ attn, float* __restrict__ al, float* __restrict__ ar)
{
    const int t    = threadIdx.x;
    const int node = blockIdx.x * 2 + (t >> 7);
    const int hc   = t & 127;
    const int h    = hc >> 5;
    const int c    = hc & 31;
    const float lv = lbuf[(size_t)node * D_OUTF + hc];
    const float rv = rbuf[(size_t)node * D_OUTF + hc];
#pragma unroll
    for (int rr = 0; rr < 3; ++rr) {
        float pa = lv * attn[rr * 256 + h * 64 + c];
        float pb = rv * attn[rr * 256 + h * 64 + 32 + c];
#pragma unroll
        for (int m = 16; m >= 1; m >>= 1) {
            pa += __shfl_xor(pa, m);
            pb += __shfl_xor(pb, m);
        }
        if (c == 0) {
            al[node * 12 + rr * 4 + h] = pa;
            ar[node * 12 + rr * 4 + h] = pb;
        }
    }
}

// ---------------------------------------------------------------------------
// K3: degree histogram (by dst)
// ---------------------------------------------------------------------------
__global__ __launch_bounds__(256) void hist_kernel(const int* __restrict__ ei,
                                                   int* __restrict__ deg)
{
    const int rr = blockIdx.y;
    const int e  = blockIdx.x * 256 + threadIdx.x;
    if (e < N_EDGES) {
        const int dst = ei[(size_t)rr * 2 * N_EDGES + N_EDGES + e];
        atomicAdd(&deg[rr * N_NODES + dst], 1);
    }
}

// ---------------------------------------------------------------------------
// K4a: per-block reduce (1024 elems/block, 256 thr x 4)
// ---------------------------------------------------------------------------
__global__ __launch_bounds__(256) void scan_reduce(const int* __restrict__ deg,
                                                   int* __restrict__ blksum)
{
    __shared__ int ws[4];
    const int tid  = threadIdx.x;
    const int lane = tid & 63;
    const int wid  = tid >> 6;
    const int idx  = blockIdx.x * SCAN_ELEMS + tid * 4;
    int t = 0;
#pragma unroll
    for (int j = 0; j < 4; ++j)
        if (idx + j < SCAN_TOTAL) t += deg[idx + j];
#pragma unroll
    for (int off = 32; off >= 1; off >>= 1) t += __shfl_xor(t, off);
    if (lane == 0) ws[wid] = t;
    __syncthreads();
    if (tid == 0) blksum[blockIdx.x] = ws[0] + ws[1] + ws[2] + ws[3];
}

// ---------------------------------------------------------------------------
// K4b: single-block exclusive scan of the 293 block sums (512 threads)
// ---------------------------------------------------------------------------
__global__ __launch_bounds__(512) void scan_mid(int* __restrict__ blksum)
{
    __shared__ int sh[512];
    const int tid = threadIdx.x;
    const int v = (tid < SCAN_NBLK) ? blksum[tid] : 0;
    sh[tid] = v;
    __syncthreads();
#pragma unroll
    for (int off = 1; off < 512; off <<= 1) {
        const int u = (tid >= off) ? sh[tid - off] : 0;
        __syncthreads();
        sh[tid] += u;
        __syncthreads();
    }
    if (tid < SCAN_NBLK) blksum[tid] = sh[tid] - v;   // exclusive
}

// ---------------------------------------------------------------------------
// K4c: per-block scan + block offset -> rowst, cursor
// ---------------------------------------------------------------------------
__global__ __launch_bounds__(256) void scan_final(const int* __restrict__ deg,
    const int* __restrict__ blkoff, int* __restrict__ rowst,
    int* __restrict__ cursor)
{
    __shared__ int wsum[4];
    __shared__ int wexcl[4];
    const int tid  = threadIdx.x;
    const int lane = tid & 63;
    const int wid  = tid >> 6;
    const int idx  = blockIdx.x * SCAN_ELEMS + tid * 4;

    const int v0 = (idx + 0 < SCAN_TOTAL) ? deg[idx + 0] : 0;
    const int v1 = (idx + 1 < SCAN_TOTAL) ? deg[idx + 1] : 0;
    const int v2 = (idx + 2 < SCAN_TOTAL) ? deg[idx + 2] : 0;
    const int v3 = (idx + 3 < SCAN_TOTAL) ? deg[idx + 3] : 0;
    const int tsum = v0 + v1 + v2 + v3;
    int inc = tsum;
#pragma unroll
    for (int off = 1; off < 64; off <<= 1) {
        const int u = __shfl_up(inc, off);
        if (lane >= off) inc += u;
    }
    if (lane == 63) wsum[wid] = inc;
    __syncthreads();
    if (tid == 0) {
        int s = 0;
#pragma unroll
        for (int i = 0; i < 4; ++i) { const int t2 = wsum[i]; wexcl[i] = s; s += t2; }
    }
    __syncthreads();
    const int start = blkoff[blockIdx.x] + wexcl[wid] + (inc - tsum);
    if (idx + 0 < SCAN_TOTAL) { rowst[idx + 0] = start; cursor[idx + 0] = start; }
    const int s1 = start + v0;
    if (idx + 1 < SCAN_TOTAL) { rowst[idx + 1] = s1; cursor[idx + 1] = s1; }
    const int s2 = s1 + v1;
    if (idx + 2 < SCAN_TOTAL) { rowst[idx + 2] = s2; cursor[idx + 2] = s2; }
    const int s3 = s2 + v2;
    if (idx + 3 < SCAN_TOTAL) { rowst[idx + 3] = s3; cursor[idx + 3] = s3; }
}

// ---------------------------------------------------------------------------
// K5: scatter src ids into CSR buckets
// ---------------------------------------------------------------------------
__global__ __launch_bounds__(256) void scatter_kernel(const int* __restrict__ ei,
    int* __restrict__ cursor, int* __restrict__ colall)
{
    const int rr = blockIdx.y;
    const int e  = blockIdx.x * 256 + threadIdx.x;
    if (e < N_EDGES) {
        const int src = ei[(size_t)rr * 2 * N_EDGES + e];
        const int dst = ei[(size_t)rr * 2 * N_EDGES + N_EDGES + e];
        const int pos = atomicAdd(&cursor[rr * N_NODES + dst], 1);
        colall[pos] = src;
    }
}

// ---------------------------------------------------------------------------
// K6: fused per-node aggregation + relation-level beta softmax + output.
// One 64-lane wave per node; lane L owns channel PAIR {2L, 2L+1}, both in
// head h = L>>4 (16 consecutive lanes = one head).  Per edge: ONE al gather,
// ONE leaky+exp, ONE coalesced float2 lbuf load per lane.
// ---------------------------------------------------------------------------
__global__ __launch_bounds__(256) void aggregate_kernel(
    const float* __restrict__ lbuf, const float* __restrict__ rbuf,
    const float* __restrict__ al,   const float* __restrict__ ar,
    const int* __restrict__ rowst,  const int* __restrict__ deg,
    const int* __restrict__ colall,
    const float* __restrict__ rel_attn_l, const float* __restrict__ rel_attn_r,
    const float* __restrict__ rel_bias,   float* __restrict__ out)
{
    const int n    = (blockIdx.x * blockDim.x + threadIdx.x) >> 6;
    const int lane = threadIdx.x & 63;
    if (n >= N_NODES) return;

    const int h  = lane >> 4;       // head 0..3 (16 lanes per head)
    const int c2 = lane * 2;        // channel pair base (0..126)

    float arr[3];
#pragma unroll
    for (int rr = 0; rr < 3; ++rr) arr[rr] = ar[n * 12 + rr * 4 + h];

    float ex[3] = {0.f, 0.f, 0.f}, ey[3] = {0.f, 0.f, 0.f};
    float den[3] = {0.f, 0.f, 0.f};

#pragma unroll
    for (int rr = 0; rr < 3; ++rr) {
        const int start = rowst[rr * N_NODES + n];
        const int cnt   = deg[rr * N_NODES + n];
        for (int base = 0; base < cnt; base += 64) {
            const int m = min(64, cnt - base);
            const int srcv = (lane < m) ? colall[start + base + lane] : 0;
            int i = 0;
            for (; i + 1 < m; i += 2) {
                const int sA = __shfl(srcv, i);
                const int sB = __shfl(srcv, i + 1);
                const float alA = al[sA * 12 + rr * 4 + h];
                const float alB = al[sB * 12 + rr * 4 + h];
                const float2 lA = *reinterpret_cast<const float2*>(lbuf + (size_t)sA * D_OUTF + c2);
                const float2 lB = *reinterpret_cast<const float2*>(lbuf + (size_t)sB * D_OUTF + c2);
                float aA = alA + arr[rr];
                float aB = alB + arr[rr];
                aA = (aA > 0.f) ? aA : 0.2f * aA;
                aB = (aB > 0.f) ? aB : 0.2f * aB;
                const float wA = __expf(aA);
                const float wB = __expf(aB);
                den[rr] += wA + wB;
                ex[rr] = fmaf(wA, lA.x, ex[rr]);
                ey[rr] = fmaf(wA, lA.y, ey[rr]);
                ex[rr] = fmaf(wB, lB.x, ex[rr]);
                ey[rr] = fmaf(wB, lB.y, ey[rr]);
            }
            if (i < m) {
                const int src = __shfl(srcv, i);
                const float2 lv = *reinterpret_cast<const float2*>(lbuf + (size_t)src * D_OUTF + c2);
                float a = al[src * 12 + rr * 4 + h] + arr[rr];
                a = (a > 0.f) ? a : 0.2f * a;
                const float w = __expf(a);
                den[rr] += w;
                ex[rr] = fmaf(w, lv.x, ex[rr]);
                ey[rr] = fmaf(w, lv.y, ey[rr]);
            }
        }
    }

    // normalized relation embeddings + self slot
    float e0[4], e1[4];
#pragma unroll
    for (int rr = 0; rr < 3; ++rr) {
        const float inv = 1.f / (den[rr] + 1e-16f);
        e0[rr] = ex[rr] * inv;
        e1[rr] = ey[rr] * inv;
    }
    const float2 lself = *reinterpret_cast<const float2*>(lbuf + (size_t)n * D_OUTF + c2);
    e0[3] = lself.x;
    e1[3] = lself.y;

    // relation-level beta attention
    const float2 rv   = *reinterpret_cast<const float2*>(rbuf + (size_t)n * D_OUTF + c2);
    const float2 ral2 = *reinterpret_cast<const float2*>(rel_attn_l + c2);
    const float bl0 = fmaxf(rv.x * ral2.x, 0.f);
    const float bl1 = fmaxf(rv.y * ral2.y, 0.f);

    float beta[4];
#pragma unroll
    for (int s = 0; s < 4; ++s) {
        const float2 rar2 = *reinterpret_cast<const float2*>(rel_attn_r + s * D_OUTF + c2);
        const float br0 = fmaxf(e0[s] * rar2.x, 0.f);
        const float br1 = fmaxf(e1[s] * rar2.y, 0.f);
        float p = fmaf(bl0, br0, bl1 * br1);
        // reduce over the 16-lane head group
#pragma unroll
        for (int m = 8; m >= 1; m >>= 1) p += __shfl_xor(p, m);
        beta[s] = p + rel_bias[s];
    }

    // softmax over the 4 relation slots (per head)
    const float mx = fmaxf(fmaxf(beta[0], beta[1]), fmaxf(beta[2], beta[3]));
    float ssum = 0.f;
#pragma unroll
    for (int s = 0; s < 4; ++s) { beta[s] = __expf(beta[s] - mx); ssum += beta[s]; }
    const float isum = 1.f / ssum;
    float o0 = 0.f, o1 = 0.f;
#pragma unroll
    for (int s = 0; s < 4; ++s) {
        const float b = beta[s] * isum;
        o0 = fmaf(e0[s], b, o0);
        o1 = fmaf(e1[s], b, o1);
    }
    float2 ov;
    ov.x = fmaxf(o0, 0.f);
    ov.y = fmaxf(o1, 0.f);
    *reinterpret_cast<float2*>(out + (size_t)n * D_OUTF + c2) = ov;
}

// ---------------------------------------------------------------------------
extern "C" void kernel_launch(void* const* d_in, const int* in_sizes, int n_in,
                              void* d_out, int out_size, void* d_ws, size_t ws_size,
                              hipStream_t stream)
{
    const float* x     = (const float*)d_in[0];
    const int*   ei    = (const int*)  d_in[1];
    const float* Wl    = (const float*)d_in[2];
    const float* bl    = (const float*)d_in[3];
    const float* Wr    = (const float*)d_in[4];
    const float* br    = (const float*)d_in[5];
    const float* attn  = (const float*)d_in[6];
    const float* ral   = (const float*)d_in[7];
    const float* rar   = (const float*)d_in[8];
    const float* rbias = (const float*)d_in[9];
    float* out = (float*)d_out;

    char* ws = (char*)d_ws;
    size_t off = 0;
    float* lbuf   = (float*)(ws + off); off += (size_t)N_NODES * D_OUTF * 4;   // 51.2 MB
    float* rbuf   = (float*)(ws + off); off += (size_t)N_NODES * D_OUTF * 4;   // 51.2 MB
    float* al     = (float*)(ws + off); off += (size_t)N_NODES * 12 * 4;       // 4.8 MB
    float* ar     = (float*)(ws + off); off += (size_t)N_NODES * 12 * 4;       // 4.8 MB
    int*   deg    = (int*)  (ws + off); off += (size_t)3 * N_NODES * 4;        // 1.2 MB
    int*   rowst  = (int*)  (ws + off); off += (size_t)3 * N_NODES * 4;        // 1.2 MB
    int*   cursor = (int*)  (ws + off); off += (size_t)3 * N_NODES * 4;        // 1.2 MB
    int*   colall = (int*)  (ws + off); off += (size_t)3 * N_EDGES * 4;        // 7.2 MB
    int*   blksum = (int*)  (ws + off); off += (size_t)512 * 4;
    unsigned short* wt = (unsigned short*)(ws + off); off += (size_t)2 * 2 * 128 * 256 * 2; // 256 KB

    hipMemsetAsync(deg, 0, (size_t)3 * N_NODES * 4, stream);

    wt_prep<<<dim3(256, 2), 128, 0, stream>>>(Wl, Wr, wt);
    proj_mfma<<<dim3((N_NODES + 63) / 64, 2), 256, 0, stream>>>(
        x, wt, bl, br, lbuf, rbuf);

    alar_kernel<<<N_NODES / 2, 256, 0, stream>>>(lbuf, rbuf, attn, al, ar);

    dim3 eg((N_EDGES + 255) / 256, 3);
    hist_kernel<<<eg, 256, 0, stream>>>(ei, deg);
    scan_reduce<<<SCAN_NBLK, 256, 0, stream>>>(deg, blksum);
    scan_mid<<<1, 512, 0, stream>>>(blksum);
    scan_final<<<SCAN_NBLK, 256, 0, stream>>>(deg, blksum, rowst, cursor);
    scatter_kernel<<<eg, 256, 0, stream>>>(ei, cursor, colall);

    aggregate_kernel<<<N_NODES / 4, 256, 0, stream>>>(
        lbuf, rbuf, al, ar, rowst, deg, colall, ral, rar, rbias, out);
}

// Round 8
// 476.126 us; speedup vs baseline: 1.1072x; 1.1072x over previous
//
#include <hip/hip_runtime.h>
#include <hip/hip_bf16.h>

#define N_NODES 100000
#define N_EDGES 600000
#define N_REL   3
#define D_INF   256
#define D_OUTF  128

#define SCAN_TOTAL (3 * N_NODES)                 // 300000
#define SCAN_ELEMS 1024                          // elems per block
#define SCAN_NBLK  ((SCAN_TOTAL + SCAN_ELEMS - 1) / SCAN_ELEMS)  // 293

typedef __attribute__((ext_vector_type(8))) short          bf16x8;
typedef __attribute__((ext_vector_type(8))) unsigned short ushort8;
typedef __attribute__((ext_vector_type(4))) float          f32x4;

// row stride (in bf16 elems) for LDS tiles: 72*2=144B -> 16B-aligned, and
// 16 rows spread over banks with only 2-way aliasing (free per m136)
#define LPAD 72

__device__ __forceinline__ unsigned short bf16_rne(float v) {
    unsigned int b = __float_as_uint(v);
    b += 0x7FFFu + ((b >> 16) & 1u);
    return (unsigned short)(b >> 16);
}

// ---------------------------------------------------------------------------
// K0: W [256][128] f32  ->  Wt_{hi,lo} [128 cols][256 k] bf16  (per W)
// ---------------------------------------------------------------------------
__global__ __launch_bounds__(128) void wt_prep(
    const float* __restrict__ Wl, const float* __restrict__ Wr,
    unsigned short* __restrict__ wt)
{
    const int k = blockIdx.x;      // 0..255
    const int w = blockIdx.y;      // 0,1
    const int n = threadIdx.x;     // 0..127
    const float v = (w ? Wr : Wl)[(size_t)k * D_OUTF + n];
    const unsigned short h = bf16_rne(v);
    const float fhi = __uint_as_float(((unsigned int)h) << 16);
    const unsigned short g = bf16_rne(v - fhi);
    const size_t base = (size_t)w * 2 * 128 * 256;
    wt[base + (size_t)n * 256 + k]          = h;
    wt[base + 32768 + (size_t)n * 256 + k]  = g;
}

// ---------------------------------------------------------------------------
// K1: projection GEMM via split-bf16 MFMA (C = xhi*Whi + xhi*Wlo + xlo*Whi)
// ---------------------------------------------------------------------------
__global__ __launch_bounds__(256) void proj_mfma(
    const float* __restrict__ x, const unsigned short* __restrict__ wt,
    const float* __restrict__ bl, const float* __restrict__ br,
    float* __restrict__ lbuf, float* __restrict__ rbuf)
{
    __shared__ unsigned short xs[2][64][LPAD];    // x tile   hi/lo
    __shared__ unsigned short ws2[2][128][LPAD];  // W^T tile hi/lo

    const int tid  = threadIdx.x;
    const int nb   = blockIdx.x * 64;
    const int w    = blockIdx.y;
    const unsigned short* wtw = wt + (size_t)w * 2 * 128 * 256;
    const float* bias = w ? br : bl;
    float*       obuf = w ? rbuf : lbuf;

    const int lane = tid & 63;
    const int wv   = tid >> 6;      // wave 0..3
    const int rowf = lane & 15;
    const int kgrp = lane >> 4;     // 0..3

    f32x4 acc[8];
#pragma unroll
    for (int cf = 0; cf < 8; ++cf) acc[cf] = (f32x4){0.f, 0.f, 0.f, 0.f};

    float bv[8];
#pragma unroll
    for (int cf = 0; cf < 8; ++cf) bv[cf] = bias[cf * 16 + rowf];

    for (int kb = 0; kb < D_INF; kb += 64) {
        __syncthreads();
        // ---- stage x tile: thread t -> row t>>2, 16 k's at (t&3)*16
        {
            const int r   = tid >> 2;
            const int seg = tid & 3;
            int rowg = nb + r; if (rowg >= N_NODES) rowg = N_NODES - 1;
            const float* src = x + (size_t)rowg * D_INF + kb + seg * 16;
#pragma unroll
            for (int q2 = 0; q2 < 2; ++q2) {
                const float4 v0 = *reinterpret_cast<const float4*>(src + q2 * 8);
                const float4 v1 = *reinterpret_cast<const float4*>(src + q2 * 8 + 4);
                const float vv[8] = {v0.x, v0.y, v0.z, v0.w, v1.x, v1.y, v1.z, v1.w};
                ushort8 hv, gv;
#pragma unroll
                for (int q = 0; q < 8; ++q) {
                    const unsigned short h = bf16_rne(vv[q]);
                    hv[q] = h;
                    const float fhi = __uint_as_float(((unsigned int)h) << 16);
                    gv[q] = bf16_rne(vv[q] - fhi);
                }
                *reinterpret_cast<ushort8*>(&xs[0][r][seg * 16 + q2 * 8]) = hv;
                *reinterpret_cast<ushort8*>(&xs[1][r][seg * 16 + q2 * 8]) = gv;
            }
        }
        // ---- stage W^T tile: thread t -> col n=t>>1, 32 k's at (t&1)*32
        {
            const int n    = tid >> 1;
            const int half = tid & 1;
            const uint4* sh = reinterpret_cast<const uint4*>(wtw + (size_t)n * 256 + kb + half * 32);
            const uint4* sl = reinterpret_cast<const uint4*>(wtw + 32768 + (size_t)n * 256 + kb + half * 32);
            uint4* dh = reinterpret_cast<uint4*>(&ws2[0][n][half * 32]);
            uint4* dl = reinterpret_cast<uint4*>(&ws2[1][n][half * 32]);
#pragma unroll
            for (int q = 0; q < 4; ++q) { dh[q] = sh[q]; dl[q] = sl[q]; }
        }
        __syncthreads();

        // ---- MFMA over the 2 k32-steps of this BK
#pragma unroll
        for (int kk = 0; kk < 2; ++kk) {
            const int ko = kk * 32 + kgrp * 8;
            const bf16x8 ahi = *reinterpret_cast<const bf16x8*>(&xs[0][wv * 16 + rowf][ko]);
            const bf16x8 alo = *reinterpret_cast<const bf16x8*>(&xs[1][wv * 16 + rowf][ko]);
#pragma unroll
            for (int cf = 0; cf < 8; ++cf) {
                const bf16x8 bhi = *reinterpret_cast<const bf16x8*>(&ws2[0][cf * 16 + rowf][ko]);
                const bf16x8 blo = *reinterpret_cast<const bf16x8*>(&ws2[1][cf * 16 + rowf][ko]);
                acc[cf] = __builtin_amdgcn_mfma_f32_16x16x32_bf16(ahi, bhi, acc[cf], 0, 0, 0);
                acc[cf] = __builtin_amdgcn_mfma_f32_16x16x32_bf16(ahi, blo, acc[cf], 0, 0, 0);
                acc[cf] = __builtin_amdgcn_mfma_f32_16x16x32_bf16(alo, bhi, acc[cf], 0, 0, 0);
            }
        }
    }

    // ---- epilogue: bias + relu + store (C layout: row=kgrp*4+j, col=rowf)
#pragma unroll
    for (int cf = 0; cf < 8; ++cf) {
#pragma unroll
        for (int j = 0; j < 4; ++j) {
            const int node = nb + wv * 16 + kgrp * 4 + j;
            if (node < N_NODES)
                obuf[(size_t)node * D_OUTF + cf * 16 + rowf] =
                    fmaxf(acc[cf][j] + bv[cf], 0.f);
        }
    }
}

// ---------------------------------------------------------------------------
// K2: per-node attention scalars + bf16 copy of l (for aggregate gathers)
// ---------------------------------------------------------------------------
__global__ __launch_bounds__(256) void alar_kernel(
    const float* __restrict__ lbuf, const float* __restrict__ rbuf,
    const float* __restrict__ attn, float* __restrict__ al, float* __restrict__ ar,
    unsigned short* __restrict__ lbf)
{
    const int t    = threadIdx.x;
    const int node = blockIdx.x * 2 + (t >> 7);
    const int hc   = t & 127;
    const int h    = hc >> 5;
    const int c    = hc & 31;
    const float lv = lbuf[(size_t)node * D_OUTF + hc];
    const float rv = rbuf[(size_t)node * D_OUTF + hc];
    lbf[(size_t)node * D_OUTF + hc] = bf16_rne(lv);
#pragma unroll
    for (int rr = 0; rr < 3; ++rr) {
        float pa = lv * attn[rr * 256 + h * 64 + c];
        float pb = rv * attn[rr * 256 + h * 64 + 32 + c];
#pragma unroll
        for (int m = 16; m >= 1; m >>= 1) {
            pa += __shfl_xor(pa, m);
            pb += __shfl_xor(pb, m);
        }
        if (c == 0) {
            al[node * 12 + rr * 4 + h] = pa;
            ar[node * 12 + rr * 4 + h] = pb;
        }
    }
}

// ---------------------------------------------------------------------------
// K3: degree histogram (by dst)
// ---------------------------------------------------------------------------
__global__ __launch_bounds__(256) void hist_kernel(const int* __restrict__ ei,
                                                   int* __restrict__ deg)
{
    const int rr = blockIdx.y;
    const int e  = blockIdx.x * 256 + threadIdx.x;
    if (e < N_EDGES) {
        const int dst = ei[(size_t)rr * 2 * N_EDGES + N_EDGES + e];
        atomicAdd(&deg[rr * N_NODES + dst], 1);
    }
}

// ---------------------------------------------------------------------------
// K4a: per-block reduce (1024 elems/block, 256 thr x 4)
// ---------------------------------------------------------------------------
__global__ __launch_bounds__(256) void scan_reduce(const int* __restrict__ deg,
                                                   int* __restrict__ blksum)
{
    __shared__ int ws[4];
    const int tid  = threadIdx.x;
    const int lane = tid & 63;
    const int wid  = tid >> 6;
    const int idx  = blockIdx.x * SCAN_ELEMS + tid * 4;
    int t = 0;
#pragma unroll
    for (int j = 0; j < 4; ++j)
        if (idx + j < SCAN_TOTAL) t += deg[idx + j];
#pragma unroll
    for (int off = 32; off >= 1; off >>= 1) t += __shfl_xor(t, off);
    if (lane == 0) ws[wid] = t;
    __syncthreads();
    if (tid == 0) blksum[blockIdx.x] = ws[0] + ws[1] + ws[2] + ws[3];
}

// ---------------------------------------------------------------------------
// K4b: single-block exclusive scan of the 293 block sums (512 threads)
// ---------------------------------------------------------------------------
__global__ __launch_bounds__(512) void scan_mid(int* __restrict__ blksum)
{
    __shared__ int sh[512];
    const int tid = threadIdx.x;
    const int v = (tid < SCAN_NBLK) ? blksum[tid] : 0;
    sh[tid] = v;
    __syncthreads();
#pragma unroll
    for (int off = 1; off < 512; off <<= 1) {
        const int u = (tid >= off) ? sh[tid - off] : 0;
        __syncthreads();
        sh[tid] += u;
        __syncthreads();
    }
    if (tid < SCAN_NBLK) blksum[tid] = sh[tid] - v;   // exclusive
}

// ---------------------------------------------------------------------------
// K4c: per-block scan + block offset -> rowst, cursor
// ---------------------------------------------------------------------------
__global__ __launch_bounds__(256) void scan_final(const int* __restrict__ deg,
    const int* __restrict__ blkoff, int* __restrict__ rowst,
    int* __restrict__ cursor)
{
    __shared__ int wsum[4];
    __shared__ int wexcl[4];
    const int tid  = threadIdx.x;
    const int lane = tid & 63;
    const int wid  = tid >> 6;
    const int idx  = blockIdx.x * SCAN_ELEMS + tid * 4;

    const int v0 = (idx + 0 < SCAN_TOTAL) ? deg[idx + 0] : 0;
    const int v1 = (idx + 1 < SCAN_TOTAL) ? deg[idx + 1] : 0;
    const int v2 = (idx + 2 < SCAN_TOTAL) ? deg[idx + 2] : 0;
    const int v3 = (idx + 3 < SCAN_TOTAL) ? deg[idx + 3] : 0;
    const int tsum = v0 + v1 + v2 + v3;
    int inc = tsum;
#pragma unroll
    for (int off = 1; off < 64; off <<= 1) {
        const int u = __shfl_up(inc, off);
        if (lane >= off) inc += u;
    }
    if (lane == 63) wsum[wid] = inc;
    __syncthreads();
    if (tid == 0) {
        int s = 0;
#pragma unroll
        for (int i = 0; i < 4; ++i) { const int t2 = wsum[i]; wexcl[i] = s; s += t2; }
    }
    __syncthreads();
    const int start = blkoff[blockIdx.x] + wexcl[wid] + (inc - tsum);
    if (idx + 0 < SCAN_TOTAL) { rowst[idx + 0] = start; cursor[idx + 0] = start; }
    const int s1 = start + v0;
    if (idx + 1 < SCAN_TOTAL) { rowst[idx + 1] = s1; cursor[idx + 1] = s1; }
    const int s2 = s1 + v1;
    if (idx + 2 < SCAN_TOTAL) { rowst[idx + 2] = s2; cursor[idx + 2] = s2; }
    const int s3 = s2 + v2;
    if (idx + 3 < SCAN_TOTAL) { rowst[idx + 3] = s3; cursor[idx + 3] = s3; }
}

// ---------------------------------------------------------------------------
// K5: scatter src ids into CSR buckets
// ---------------------------------------------------------------------------
__global__ __launch_bounds__(256) void scatter_kernel(const int* __restrict__ ei,
    int* __restrict__ cursor, int* __restrict__ colall)
{
    const int rr = blockIdx.y;
    const int e  = blockIdx.x * 256 + threadIdx.x;
    if (e < N_EDGES) {
        const int src = ei[(size_t)rr * 2 * N_EDGES + e];
        const int dst = ei[(size_t)rr * 2 * N_EDGES + N_EDGES + e];
        const int pos = atomicAdd(&cursor[rr * N_NODES + dst], 1);
        colall[pos] = src;
    }
}

// ---------------------------------------------------------------------------
// K6: fused per-node aggregation + relation-level beta softmax + output.
// One 64-lane wave per node; lane L owns channel PAIR {2L, 2L+1}, head L>>4.
// Edge messages gathered from the bf16 copy of l: ONE dword per lane per
// edge (256B per row, half the f32 traffic).  Self slot / rbuf stay f32.
// ---------------------------------------------------------------------------
__global__ __launch_bounds__(256) void aggregate_kernel(
    const float* __restrict__ lbuf, const unsigned int* __restrict__ lbf32,
    const float* __restrict__ rbuf,
    const float* __restrict__ al,   const float* __restrict__ ar,
    const int* __restrict__ rowst,  const int* __restrict__ deg,
    const int* __restrict__ colall,
    const float* __restrict__ rel_attn_l, const float* __restrict__ rel_attn_r,
    const float* __restrict__ rel_bias,   float* __restrict__ out)
{
    const int n    = (blockIdx.x * blockDim.x + threadIdx.x) >> 6;
    const int lane = threadIdx.x & 63;
    if (n >= N_NODES) return;

    const int h  = lane >> 4;       // head 0..3 (16 lanes per head)
    const int c2 = lane * 2;        // channel pair base (0..126)

    float arr[3];
#pragma unroll
    for (int rr = 0; rr < 3; ++rr) arr[rr] = ar[n * 12 + rr * 4 + h];

    float ex[3] = {0.f, 0.f, 0.f}, ey[3] = {0.f, 0.f, 0.f};
    float den[3] = {0.f, 0.f, 0.f};

#pragma unroll
    for (int rr = 0; rr < 3; ++rr) {
        const int start = rowst[rr * N_NODES + n];
        const int cnt   = deg[rr * N_NODES + n];
        for (int base = 0; base < cnt; base += 64) {
            const int m = min(64, cnt - base);
            const int srcv = (lane < m) ? colall[start + base + lane] : 0;
            int i = 0;
            for (; i + 1 < m; i += 2) {
                const int sA = __shfl(srcv, i);
                const int sB = __shfl(srcv, i + 1);
                const float alA = al[sA * 12 + rr * 4 + h];
                const float alB = al[sB * 12 + rr * 4 + h];
                const unsigned int uA = lbf32[(size_t)sA * 64 + lane];
                const unsigned int uB = lbf32[(size_t)sB * 64 + lane];
                float aA = alA + arr[rr];
                float aB = alB + arr[rr];
                aA = (aA > 0.f) ? aA : 0.2f * aA;
                aB = (aB > 0.f) ? aB : 0.2f * aB;
                const float wA = __expf(aA);
                const float wB = __expf(aB);
                const float lAx = __uint_as_float(uA << 16);
                const float lAy = __uint_as_float(uA & 0xFFFF0000u);
                const float lBx = __uint_as_float(uB << 16);
                const float lBy = __uint_as_float(uB & 0xFFFF0000u);
                den[rr] += wA + wB;
                ex[rr] = fmaf(wA, lAx, ex[rr]);
                ey[rr] = fmaf(wA, lAy, ey[rr]);
                ex[rr] = fmaf(wB, lBx, ex[rr]);
                ey[rr] = fmaf(wB, lBy, ey[rr]);
            }
            if (i < m) {
                const int src = __shfl(srcv, i);
                const unsigned int u = lbf32[(size_t)src * 64 + lane];
                float a = al[src * 12 + rr * 4 + h] + arr[rr];
                a = (a > 0.f) ? a : 0.2f * a;
                const float w = __expf(a);
                den[rr] += w;
                ex[rr] = fmaf(w, __uint_as_float(u << 16), ex[rr]);
                ey[rr] = fmaf(w, __uint_as_float(u & 0xFFFF0000u), ey[rr]);
            }
        }
    }

    // normalized relation embeddings + self slot (self in f32)
    float e0[4], e1[4];
#pragma unroll
    for (int rr = 0; rr < 3; ++rr) {
        const float inv = 1.f / (den[rr] + 1e-16f);
        e0[rr] = ex[rr] * inv;
        e1[rr] = ey[rr] * inv;
    }
    const float2 lself = *reinterpret_cast<const float2*>(lbuf + (size_t)n * D_OUTF + c2);
    e0[3] = lself.x;
    e1[3] = lself.y;

    // relation-level beta attention
    const float2 rv   = *reinterpret_cast<const float2*>(rbuf + (size_t)n * D_OUTF + c2);
    const float2 ral2 = *reinterpret_cast<const float2*>(rel_attn_l + c2);
    const float bl0 = fmaxf(rv.x * ral2.x, 0.f);
    const float bl1 = fmaxf(rv.y * ral2.y, 0.f);

    float beta[4];
#pragma unroll
    for (int s = 0; s < 4; ++s) {
        const float2 rar2 = *reinterpret_cast<const float2*>(rel_attn_r + s * D_OUTF + c2);
        const float br0 = fmaxf(e0[s] * rar2.x, 0.f);
        const float br1 = fmaxf(e1[s] * rar2.y, 0.f);
        float p = fmaf(bl0, br0, bl1 * br1);
        // reduce over the 16-lane head group
#pragma unroll
        for (int m = 8; m >= 1; m >>= 1) p += __shfl_xor(p, m);
        beta[s] = p + rel_bias[s];
    }

    // softmax over the 4 relation slots (per head)
    const float mx = fmaxf(fmaxf(beta[0], beta[1]), fmaxf(beta[2], beta[3]));
    float ssum = 0.f;
#pragma unroll
    for (int s = 0; s < 4; ++s) { beta[s] = __expf(beta[s] - mx); ssum += beta[s]; }
    const float isum = 1.f / ssum;
    float o0 = 0.f, o1 = 0.f;
#pragma unroll
    for (int s = 0; s < 4; ++s) {
        const float b = beta[s] * isum;
        o0 = fmaf(e0[s], b, o0);
        o1 = fmaf(e1[s], b, o1);
    }
    float2 ov;
    ov.x = fmaxf(o0, 0.f);
    ov.y = fmaxf(o1, 0.f);
    *reinterpret_cast<float2*>(out + (size_t)n * D_OUTF + c2) = ov;
}

// ---------------------------------------------------------------------------
extern "C" void kernel_launch(void* const* d_in, const int* in_sizes, int n_in,
                              void* d_out, int out_size, void* d_ws, size_t ws_size,
                              hipStream_t stream)
{
    const float* x     = (const float*)d_in[0];
    const int*   ei    = (const int*)  d_in[1];
    const float* Wl    = (const float*)d_in[2];
    const float* bl    = (const float*)d_in[3];
    const float* Wr    = (const float*)d_in[4];
    const float* br    = (const float*)d_in[5];
    const float* attn  = (const float*)d_in[6];
    const float* ral   = (const float*)d_in[7];
    const float* rar   = (const float*)d_in[8];
    const float* rbias = (const float*)d_in[9];
    float* out = (float*)d_out;

    char* ws = (char*)d_ws;
    size_t off = 0;
    float* lbuf   = (float*)(ws + off); off += (size_t)N_NODES * D_OUTF * 4;   // 51.2 MB
    float* rbuf   = (float*)(ws + off); off += (size_t)N_NODES * D_OUTF * 4;   // 51.2 MB
    float* al     = (float*)(ws + off); off += (size_t)N_NODES * 12 * 4;       // 4.8 MB
    float* ar     = (float*)(ws + off); off += (size_t)N_NODES * 12 * 4;       // 4.8 MB
    int*   deg    = (int*)  (ws + off); off += (size_t)3 * N_NODES * 4;        // 1.2 MB
    int*   rowst  = (int*)  (ws + off); off += (size_t)3 * N_NODES * 4;        // 1.2 MB
    int*   cursor = (int*)  (ws + off); off += (size_t)3 * N_NODES * 4;        // 1.2 MB
    int*   colall = (int*)  (ws + off); off += (size_t)3 * N_EDGES * 4;        // 7.2 MB
    int*   blksum = (int*)  (ws + off); off += (size_t)512 * 4;
    unsigned short* wt  = (unsigned short*)(ws + off); off += (size_t)2 * 2 * 128 * 256 * 2; // 256 KB
    unsigned short* lbf = (unsigned short*)(ws + off); off += (size_t)N_NODES * D_OUTF * 2;  // 25.6 MB

    hipMemsetAsync(deg, 0, (size_t)3 * N_NODES * 4, stream);

    wt_prep<<<dim3(256, 2), 128, 0, stream>>>(Wl, Wr, wt);
    proj_mfma<<<dim3((N_NODES + 63) / 64, 2), 256, 0, stream>>>(
        x, wt, bl, br, lbuf, rbuf);

    alar_kernel<<<N_NODES / 2, 256, 0, stream>>>(lbuf, rbuf, attn, al, ar, lbf);

    dim3 eg((N_EDGES + 255) / 256, 3);
    hist_kernel<<<eg, 256, 0, stream>>>(ei, deg);
    scan_reduce<<<SCAN_NBLK, 256, 0, stream>>>(deg, blksum);
    scan_mid<<<1, 512, 0, stream>>>(blksum);
    scan_final<<<SCAN_NBLK, 256, 0, stream>>>(deg, blksum, rowst, cursor);
    scatter_kernel<<<eg, 256, 0, stream>>>(ei, cursor, colall);

    aggregate_kernel<<<N_NODES / 4, 256, 0, stream>>>(
        lbuf, (const unsigned int*)lbf, rbuf, al, ar, rowst, deg, colall,
        ral, rar, rbias, out);
}

// Round 9
// 437.457 us; speedup vs baseline: 1.2051x; 1.0884x over previous
//
#include <hip/hip_runtime.h>
#include <hip/hip_bf16.h>

#define N_NODES 100000
#define N_EDGES 600000
#define N_REL   3
#define D_INF   256
#define D_OUTF  128

#define SCAN_TOTAL (3 * N_NODES)                 // 300000
#define SCAN_ELEMS 1024                          // elems per block
#define SCAN_NBLK  ((SCAN_TOTAL + SCAN_ELEMS - 1) / SCAN_ELEMS)  // 293

typedef __attribute__((ext_vector_type(8))) short          bf16x8;
typedef __attribute__((ext_vector_type(8))) unsigned short ushort8;
typedef __attribute__((ext_vector_type(4))) float          f32x4;

// main-loop LDS row stride (bf16 elems): 144B rows, 16B aligned, ~2-way bank
#define LPAD 72
// phase-2 (attn-MFMA) LDS row stride: 272B rows
#define LTS  136

__device__ __forceinline__ unsigned short bf16_rne(float v) {
    unsigned int b = __float_as_uint(v);
    b += 0x7FFFu + ((b >> 16) & 1u);
    return (unsigned short)(b >> 16);
}

// ---------------------------------------------------------------------------
// K0: W [256][128] f32  ->  Wt_{hi,lo} [128 cols][256 k] bf16  (per W)
// ---------------------------------------------------------------------------
__global__ __launch_bounds__(128) void wt_prep(
    const float* __restrict__ Wl, const float* __restrict__ Wr,
    unsigned short* __restrict__ wt)
{
    const int k = blockIdx.x;      // 0..255
    const int w = blockIdx.y;      // 0,1
    const int n = threadIdx.x;     // 0..127
    const float v = (w ? Wr : Wl)[(size_t)k * D_OUTF + n];
    const unsigned short h = bf16_rne(v);
    const float fhi = __uint_as_float(((unsigned int)h) << 16);
    const unsigned short g = bf16_rne(v - fhi);
    const size_t base = (size_t)w * 2 * 128 * 256;
    wt[base + (size_t)n * 256 + k]          = h;
    wt[base + 32768 + (size_t)n * 256 + k]  = g;
}

// ---------------------------------------------------------------------------
// K1: projection GEMM via split-bf16 MFMA (C = xhi*Whi + xhi*Wlo + xlo*Whi)
// FUSED epilogue: al/ar via a second 12-MFMA chain against the attn matrix
// (staged sparse 128x16, split hi/lo), and lbf (bf16 copy of l) written from
// the LDS l-tile (w==0 only).  alar_kernel is gone.
// ---------------------------------------------------------------------------
__global__ __launch_bounds__(256) void proj_mfma(
    const float* __restrict__ x, const unsigned short* __restrict__ wt,
    const float* __restrict__ bl, const float* __restrict__ br,
    const float* __restrict__ attn,
    float* __restrict__ lbuf, float* __restrict__ rbuf,
    float* __restrict__ al,   float* __restrict__ ar,
    unsigned short* __restrict__ lbf)
{
    __shared__ unsigned short smem[2 * 64 * LPAD + 2 * 128 * LPAD]; // 27648 us
    unsigned short* xs0 = smem;                  // [2][64][LPAD]
    unsigned short* ws0 = smem + 2 * 64 * LPAD;  // [2][128][LPAD]
    // phase-2 aliases (main tiles dead by then):
    // lt: [2][64][LTS] at smem+0 (17408 us), at: [2][16][LTS] at smem+17408
    unsigned short* lt0 = smem;
    unsigned short* at0 = smem + 2 * 64 * LTS;

    const int tid  = threadIdx.x;
    const int nb   = blockIdx.x * 64;
    const int w    = blockIdx.y;
    const unsigned short* wtw = wt + (size_t)w * 2 * 128 * 256;
    const float* bias = w ? br : bl;
    float*       obuf = w ? rbuf : lbuf;

    const int lane = tid & 63;
    const int wv   = tid >> 6;      // wave 0..3
    const int rowf = lane & 15;
    const int kgrp = lane >> 4;     // 0..3

    f32x4 acc[8];
#pragma unroll
    for (int cf = 0; cf < 8; ++cf) acc[cf] = (f32x4){0.f, 0.f, 0.f, 0.f};

    float bv[8];
#pragma unroll
    for (int cf = 0; cf < 8; ++cf) bv[cf] = bias[cf * 16 + rowf];

    for (int kb = 0; kb < D_INF; kb += 64) {
        __syncthreads();
        // ---- stage x tile: thread t -> row t>>2, 16 k's at (t&3)*16
        {
            const int r   = tid >> 2;
            const int seg = tid & 3;
            int rowg = nb + r; if (rowg >= N_NODES) rowg = N_NODES - 1;
            const float* src = x + (size_t)rowg * D_INF + kb + seg * 16;
#pragma unroll
            for (int q2 = 0; q2 < 2; ++q2) {
                const float4 v0 = *reinterpret_cast<const float4*>(src + q2 * 8);
                const float4 v1 = *reinterpret_cast<const float4*>(src + q2 * 8 + 4);
                const float vv[8] = {v0.x, v0.y, v0.z, v0.w, v1.x, v1.y, v1.z, v1.w};
                ushort8 hv, gv;
#pragma unroll
                for (int q = 0; q < 8; ++q) {
                    const unsigned short h = bf16_rne(vv[q]);
                    hv[q] = h;
                    const float fhi = __uint_as_float(((unsigned int)h) << 16);
                    gv[q] = bf16_rne(vv[q] - fhi);
                }
                *reinterpret_cast<ushort8*>(&xs0[0 * 64 * LPAD + r * LPAD + seg * 16 + q2 * 8]) = hv;
                *reinterpret_cast<ushort8*>(&xs0[1 * 64 * LPAD + r * LPAD + seg * 16 + q2 * 8]) = gv;
            }
        }
        // ---- stage W^T tile: thread t -> col n=t>>1, 32 k's at (t&1)*32
        {
            const int n    = tid >> 1;
            const int half = tid & 1;
            const uint4* sh = reinterpret_cast<const uint4*>(wtw + (size_t)n * 256 + kb + half * 32);
            const uint4* sl = reinterpret_cast<const uint4*>(wtw + 32768 + (size_t)n * 256 + kb + half * 32);
            uint4* dh = reinterpret_cast<uint4*>(&ws0[0 * 128 * LPAD + n * LPAD + half * 32]);
            uint4* dl = reinterpret_cast<uint4*>(&ws0[1 * 128 * LPAD + n * LPAD + half * 32]);
#pragma unroll
            for (int q = 0; q < 4; ++q) { dh[q] = sh[q]; dl[q] = sl[q]; }
        }
        __syncthreads();

        // ---- MFMA over the 2 k32-steps of this BK
#pragma unroll
        for (int kk = 0; kk < 2; ++kk) {
            const int ko = kk * 32 + kgrp * 8;
            const bf16x8 ahi = *reinterpret_cast<const bf16x8*>(&xs0[0 * 64 * LPAD + (wv * 16 + rowf) * LPAD + ko]);
            const bf16x8 alo = *reinterpret_cast<const bf16x8*>(&xs0[1 * 64 * LPAD + (wv * 16 + rowf) * LPAD + ko]);
#pragma unroll
            for (int cf = 0; cf < 8; ++cf) {
                const bf16x8 bhi = *reinterpret_cast<const bf16x8*>(&ws0[0 * 128 * LPAD + (cf * 16 + rowf) * LPAD + ko]);
                const bf16x8 blo = *reinterpret_cast<const bf16x8*>(&ws0[1 * 128 * LPAD + (cf * 16 + rowf) * LPAD + ko]);
                acc[cf] = __builtin_amdgcn_mfma_f32_16x16x32_bf16(ahi, bhi, acc[cf], 0, 0, 0);
                acc[cf] = __builtin_amdgcn_mfma_f32_16x16x32_bf16(ahi, blo, acc[cf], 0, 0, 0);
                acc[cf] = __builtin_amdgcn_mfma_f32_16x16x32_bf16(alo, bhi, acc[cf], 0, 0, 0);
            }
        }
    }

    // ==== phase 2: epilogue + fused al/ar ====
    __syncthreads();   // main-tile LDS reads complete; safe to reuse

    // relu output -> f32 global + split-bf16 l-tile in LDS
#pragma unroll
    for (int cf = 0; cf < 8; ++cf) {
#pragma unroll
        for (int j = 0; j < 4; ++j) {
            const int r    = wv * 16 + kgrp * 4 + j;   // row within tile
            const int node = nb + r;
            const float o  = fmaxf(acc[cf][j] + bv[cf], 0.f);
            if (node < N_NODES)
                obuf[(size_t)node * D_OUTF + cf * 16 + rowf] = o;
            const unsigned short h = bf16_rne(o);
            const float fhi = __uint_as_float(((unsigned int)h) << 16);
            const unsigned short g = bf16_rne(o - fhi);
            lt0[0 * 64 * LTS + r * LTS + cf * 16 + rowf] = h;
            lt0[1 * 64 * LTS + r * LTS + cf * 16 + rowf] = g;
        }
    }

    // stage attn matrix A2[c][out=rr*4+h] (sparse band), split hi/lo,
    // stored TRANSPOSED: at[p][out][k=c] for contiguous B-frag reads
    {
        const int woff = w ? 32 : 0;
#pragma unroll
        for (int q = 0; q < 8; ++q) {
            const int idx = tid * 8 + q;       // 0..2047
            const int c   = idx >> 4;
            const int o   = idx & 15;
            const int rr  = o >> 2;
            const int hh  = o & 3;
            const float v = (hh == (c >> 5) && o < 12)
                          ? attn[rr * 256 + hh * 64 + woff + (c & 31)] : 0.f;
            const unsigned short h = bf16_rne(v);
            const float fhi = __uint_as_float(((unsigned int)h) << 16);
            const unsigned short g = bf16_rne(v - fhi);
            at0[0 * 16 * LTS + o * LTS + c] = h;
            at0[1 * 16 * LTS + o * LTS + c] = g;
        }
    }
    __syncthreads();

    // 12-MFMA chain: (l hi/lo) x (attn hi/lo), 4 k32 steps over 128 cols
    f32x4 acc2 = (f32x4){0.f, 0.f, 0.f, 0.f};
#pragma unroll
    for (int ks = 0; ks < 4; ++ks) {
        const int ko = ks * 32 + kgrp * 8;
        const bf16x8 ahi = *reinterpret_cast<const bf16x8*>(&lt0[0 * 64 * LTS + (wv * 16 + rowf) * LTS + ko]);
        const bf16x8 alo = *reinterpret_cast<const bf16x8*>(&lt0[1 * 64 * LTS + (wv * 16 + rowf) * LTS + ko]);
        const bf16x8 bhi = *reinterpret_cast<const bf16x8*>(&at0[0 * 16 * LTS + rowf * LTS + ko]);
        const bf16x8 blo = *reinterpret_cast<const bf16x8*>(&at0[1 * 16 * LTS + rowf * LTS + ko]);
        acc2 = __builtin_amdgcn_mfma_f32_16x16x32_bf16(ahi, bhi, acc2, 0, 0, 0);
        acc2 = __builtin_amdgcn_mfma_f32_16x16x32_bf16(ahi, blo, acc2, 0, 0, 0);
        acc2 = __builtin_amdgcn_mfma_f32_16x16x32_bf16(alo, bhi, acc2, 0, 0, 0);
    }
    // C layout: row=kgrp*4+reg (node within 16), col=rowf (out idx)
    {
        float* tab = w ? ar : al;
        if (rowf < 12) {
#pragma unroll
            for (int reg = 0; reg < 4; ++reg) {
                const int node = nb + wv * 16 + kgrp * 4 + reg;
                if (node < N_NODES) tab[(size_t)node * 12 + rowf] = acc2[reg];
            }
        }
    }

    // lbf (bf16 l copy) from LDS l-tile, coalesced  (w==0 only)
    if (w == 0) {
#pragma unroll
        for (int q = 0; q < 4; ++q) {
            const int idx = tid + q * 256;     // 0..1023 chunks of 8 us
            const int r   = idx >> 4;
            const int c8  = (idx & 15) * 8;
            const int node = nb + r;
            if (node < N_NODES)
                *reinterpret_cast<ushort8*>(&lbf[(size_t)node * D_OUTF + c8]) =
                    *reinterpret_cast<ushort8*>(&lt0[0 * 64 * LTS + r * LTS + c8]);
        }
    }
}

// ---------------------------------------------------------------------------
// K3: degree histogram (by dst)
// ---------------------------------------------------------------------------
__global__ __launch_bounds__(256) void hist_kernel(const int* __restrict__ ei,
                                                   int* __restrict__ deg)
{
    const int rr = blockIdx.y;
    const int e  = blockIdx.x * 256 + threadIdx.x;
    if (e < N_EDGES) {
        const int dst = ei[(size_t)rr * 2 * N_EDGES + N_EDGES + e];
        atomicAdd(&deg[rr * N_NODES + dst], 1);
    }
}

// ---------------------------------------------------------------------------
// K4a: per-block reduce (1024 elems/block, 256 thr x 4)
// ---------------------------------------------------------------------------
__global__ __launch_bounds__(256) void scan_reduce(const int* __restrict__ deg,
                                                   int* __restrict__ blksum)
{
    __shared__ int ws[4];
    const int tid  = threadIdx.x;
    const int lane = tid & 63;
    const int wid  = tid >> 6;
    const int idx  = blockIdx.x * SCAN_ELEMS + tid * 4;
    int t = 0;
#pragma unroll
    for (int j = 0; j < 4; ++j)
        if (idx + j < SCAN_TOTAL) t += deg[idx + j];
#pragma unroll
    for (int off = 32; off >= 1; off >>= 1) t += __shfl_xor(t, off);
    if (lane == 0) ws[wid] = t;
    __syncthreads();
    if (tid == 0) blksum[blockIdx.x] = ws[0] + ws[1] + ws[2] + ws[3];
}

// ---------------------------------------------------------------------------
// K4b: single-block exclusive scan of the 293 block sums (512 threads)
// ---------------------------------------------------------------------------
__global__ __launch_bounds__(512) void scan_mid(int* __restrict__ blksum)
{
    __shared__ int sh[512];
    const int tid = threadIdx.x;
    const int v = (tid < SCAN_NBLK) ? blksum[tid] : 0;
    sh[tid] = v;
    __syncthreads();
#pragma unroll
    for (int off = 1; off < 512; off <<= 1) {
        const int u = (tid >= off) ? sh[tid - off] : 0;
        __syncthreads();
        sh[tid] += u;
        __syncthreads();
    }
    if (tid < SCAN_NBLK) blksum[tid] = sh[tid] - v;   // exclusive
}

// ---------------------------------------------------------------------------
// K4c: per-block scan + block offset -> rowst, cursor
// ---------------------------------------------------------------------------
__global__ __launch_bounds__(256) void scan_final(const int* __restrict__ deg,
    const int* __restrict__ blkoff, int* __restrict__ rowst,
    int* __restrict__ cursor)
{
    __shared__ int wsum[4];
    __shared__ int wexcl[4];
    const int tid  = threadIdx.x;
    const int lane = tid & 63;
    const int wid  = tid >> 6;
    const int idx  = blockIdx.x * SCAN_ELEMS + tid * 4;

    const int v0 = (idx + 0 < SCAN_TOTAL) ? deg[idx + 0] : 0;
    const int v1 = (idx + 1 < SCAN_TOTAL) ? deg[idx + 1] : 0;
    const int v2 = (idx + 2 < SCAN_TOTAL) ? deg[idx + 2] : 0;
    const int v3 = (idx + 3 < SCAN_TOTAL) ? deg[idx + 3] : 0;
    const int tsum = v0 + v1 + v2 + v3;
    int inc = tsum;
#pragma unroll
    for (int off = 1; off < 64; off <<= 1) {
        const int u = __shfl_up(inc, off);
        if (lane >= off) inc += u;
    }
    if (lane == 63) wsum[wid] = inc;
    __syncthreads();
    if (tid == 0) {
        int s = 0;
#pragma unroll
        for (int i = 0; i < 4; ++i) { const int t2 = wsum[i]; wexcl[i] = s; s += t2; }
    }
    __syncthreads();
    const int start = blkoff[blockIdx.x] + wexcl[wid] + (inc - tsum);
    if (idx + 0 < SCAN_TOTAL) { rowst[idx + 0] = start; cursor[idx + 0] = start; }
    const int s1 = start + v0;
    if (idx + 1 < SCAN_TOTAL) { rowst[idx + 1] = s1; cursor[idx + 1] = s1; }
    const int s2 = s1 + v1;
    if (idx + 2 < SCAN_TOTAL) { rowst[idx + 2] = s2; cursor[idx + 2] = s2; }
    const int s3 = s2 + v2;
    if (idx + 3 < SCAN_TOTAL) { rowst[idx + 3] = s3; cursor[idx + 3] = s3; }
}

// ---------------------------------------------------------------------------
// K5: scatter src ids into CSR buckets
// ---------------------------------------------------------------------------
__global__ __launch_bounds__(256) void scatter_kernel(const int* __restrict__ ei,
    int* __restrict__ cursor, int* __restrict__ colall)
{
    const int rr = blockIdx.y;
    const int e  = blockIdx.x * 256 + threadIdx.x;
    if (e < N_EDGES) {
        const int src = ei[(size_t)rr * 2 * N_EDGES + e];
        const int dst = ei[(size_t)rr * 2 * N_EDGES + N_EDGES + e];
        const int pos = atomicAdd(&cursor[rr * N_NODES + dst], 1);
        colall[pos] = src;
    }
}

// ---------------------------------------------------------------------------
// K6: fused per-node aggregation + relation-level beta softmax + output.
// One 64-lane wave per node; lane L owns channel PAIR {2L, 2L+1}, head L>>4.
// bf16 message gathers (1 dword/lane/edge); 4-wide edge unroll for MLP.
// ---------------------------------------------------------------------------
__global__ __launch_bounds__(256) void aggregate_kernel(
    const float* __restrict__ lbuf, const unsigned int* __restrict__ lbf32,
    const float* __restrict__ rbuf,
    const float* __restrict__ al,   const float* __restrict__ ar,
    const int* __restrict__ rowst,  const int* __restrict__ deg,
    const int* __restrict__ colall,
    const float* __restrict__ rel_attn_l, const float* __restrict__ rel_attn_r,
    const float* __restrict__ rel_bias,   float* __restrict__ out)
{
    const int n    = (blockIdx.x * blockDim.x + threadIdx.x) >> 6;
    const int lane = threadIdx.x & 63;
    if (n >= N_NODES) return;

    const int h  = lane >> 4;       // head 0..3 (16 lanes per head)
    const int c2 = lane * 2;        // channel pair base (0..126)

    float arr[3];
#pragma unroll
    for (int rr = 0; rr < 3; ++rr) arr[rr] = ar[(size_t)n * 12 + rr * 4 + h];

    float ex[3] = {0.f, 0.f, 0.f}, ey[3] = {0.f, 0.f, 0.f};
    float den[3] = {0.f, 0.f, 0.f};

#pragma unroll
    for (int rr = 0; rr < 3; ++rr) {
        const int start = rowst[rr * N_NODES + n];
        const int cnt   = deg[rr * N_NODES + n];
        const int idxh  = rr * 4 + h;
        const float arv = arr[rr];
        for (int base = 0; base < cnt; base += 64) {
            const int m = min(64, cnt - base);
            const int srcv = (lane < m) ? colall[start + base + lane] : 0;
            int i = 0;
            for (; i + 3 < m; i += 4) {
                const int s0 = __shfl(srcv, i);
                const int s1 = __shfl(srcv, i + 1);
                const int s2 = __shfl(srcv, i + 2);
                const int s3 = __shfl(srcv, i + 3);
                const float a0 = al[(size_t)s0 * 12 + idxh];
                const float a1 = al[(size_t)s1 * 12 + idxh];
                const float a2 = al[(size_t)s2 * 12 + idxh];
                const float a3 = al[(size_t)s3 * 12 + idxh];
                const unsigned int u0 = lbf32[(size_t)s0 * 64 + lane];
                const unsigned int u1 = lbf32[(size_t)s1 * 64 + lane];
                const unsigned int u2 = lbf32[(size_t)s2 * 64 + lane];
                const unsigned int u3 = lbf32[(size_t)s3 * 64 + lane];
                float t0 = a0 + arv, t1 = a1 + arv, t2 = a2 + arv, t3 = a3 + arv;
                t0 = fmaxf(t0, 0.2f * t0);
                t1 = fmaxf(t1, 0.2f * t1);
                t2 = fmaxf(t2, 0.2f * t2);
                t3 = fmaxf(t3, 0.2f * t3);
                const float w0 = __expf(t0), w1 = __expf(t1);
                const float w2 = __expf(t2), w3 = __expf(t3);
                den[rr] += (w0 + w1) + (w2 + w3);
                ex[rr] = fmaf(w0, __uint_as_float(u0 << 16), ex[rr]);
                ey[rr] = fmaf(w0, __uint_as_float(u0 & 0xFFFF0000u), ey[rr]);
                ex[rr] = fmaf(w1, __uint_as_float(u1 << 16), ex[rr]);
                ey[rr] = fmaf(w1, __uint_as_float(u1 & 0xFFFF0000u), ey[rr]);
                ex[rr] = fmaf(w2, __uint_as_float(u2 << 16), ex[rr]);
                ey[rr] = fmaf(w2, __uint_as_float(u2 & 0xFFFF0000u), ey[rr]);
                ex[rr] = fmaf(w3, __uint_as_float(u3 << 16), ex[rr]);
                ey[rr] = fmaf(w3, __uint_as_float(u3 & 0xFFFF0000u), ey[rr]);
            }
            for (; i < m; ++i) {
                const int src = __shfl(srcv, i);
                const unsigned int u = lbf32[(size_t)src * 64 + lane];
                float a = al[(size_t)src * 12 + idxh] + arv;
                a = fmaxf(a, 0.2f * a);
                const float w = __expf(a);
                den[rr] += w;
                ex[rr] = fmaf(w, __uint_as_float(u << 16), ex[rr]);
                ey[rr] = fmaf(w, __uint_as_float(u & 0xFFFF0000u), ey[rr]);
            }
        }
    }

    // normalized relation embeddings + self slot (self in f32)
    float e0[4], e1[4];
#pragma unroll
    for (int rr = 0; rr < 3; ++rr) {
        const float inv = 1.f / (den[rr] + 1e-16f);
        e0[rr] = ex[rr] * inv;
        e1[rr] = ey[rr] * inv;
    }
    const float2 lself = *reinterpret_cast<const float2*>(lbuf + (size_t)n * D_OUTF + c2);
    e0[3] = lself.x;
    e1[3] = lself.y;

    // relation-level beta attention
    const float2 rv   = *reinterpret_cast<const float2*>(rbuf + (size_t)n * D_OUTF + c2);
    const float2 ral2 = *reinterpret_cast<const float2*>(rel_attn_l + c2);
    const float bl0 = fmaxf(rv.x * ral2.x, 0.f);
    const float bl1 = fmaxf(rv.y * ral2.y, 0.f);

    float beta[4];
#pragma unroll
    for (int s = 0; s < 4; ++s) {
        const float2 rar2 = *reinterpret_cast<const float2*>(rel_attn_r + s * D_OUTF + c2);
        const float br0 = fmaxf(e0[s] * rar2.x, 0.f);
        const float br1 = fmaxf(e1[s] * rar2.y, 0.f);
        float p = fmaf(bl0, br0, bl1 * br1);
        // reduce over the 16-lane head group
#pragma unroll
        for (int m = 8; m >= 1; m >>= 1) p += __shfl_xor(p, m);
        beta[s] = p + rel_bias[s];
    }

    // softmax over the 4 relation slots (per head)
    const float mx = fmaxf(fmaxf(beta[0], beta[1]), fmaxf(beta[2], beta[3]));
    float ssum = 0.f;
#pragma unroll
    for (int s = 0; s < 4; ++s) { beta[s] = __expf(beta[s] - mx); ssum += beta[s]; }
    const float isum = 1.f / ssum;
    float o0 = 0.f, o1 = 0.f;
#pragma unroll
    for (int s = 0; s < 4; ++s) {
        const float b = beta[s] * isum;
        o0 = fmaf(e0[s], b, o0);
        o1 = fmaf(e1[s], b, o1);
    }
    float2 ov;
    ov.x = fmaxf(o0, 0.f);
    ov.y = fmaxf(o1, 0.f);
    *reinterpret_cast<float2*>(out + (size_t)n * D_OUTF + c2) = ov;
}

// ---------------------------------------------------------------------------
extern "C" void kernel_launch(void* const* d_in, const int* in_sizes, int n_in,
                              void* d_out, int out_size, void* d_ws, size_t ws_size,
                              hipStream_t stream)
{
    const float* x     = (const float*)d_in[0];
    const int*   ei    = (const int*)  d_in[1];
    const float* Wl    = (const float*)d_in[2];
    const float* bl    = (const float*)d_in[3];
    const float* Wr    = (const float*)d_in[4];
    const float* br    = (const float*)d_in[5];
    const float* attn  = (const float*)d_in[6];
    const float* ral   = (const float*)d_in[7];
    const float* rar   = (const float*)d_in[8];
    const float* rbias = (const float*)d_in[9];
    float* out = (float*)d_out;

    char* ws = (char*)d_ws;
    size_t off = 0;
    float* lbuf   = (float*)(ws + off); off += (size_t)N_NODES * D_OUTF * 4;   // 51.2 MB
    float* rbuf   = (float*)(ws + off); off += (size_t)N_NODES * D_OUTF * 4;   // 51.2 MB
    float* al     = (float*)(ws + off); off += (size_t)N_NODES * 12 * 4;       // 4.8 MB
    float* ar     = (float*)(ws + off); off += (size_t)N_NODES * 12 * 4;       // 4.8 MB
    int*   deg    = (int*)  (ws + off); off += (size_t)3 * N_NODES * 4;        // 1.2 MB
    int*   rowst  = (int*)  (ws + off); off += (size_t)3 * N_NODES * 4;        // 1.2 MB
    int*   cursor = (int*)  (ws + off); off += (size_t)3 * N_NODES * 4;        // 1.2 MB
    int*   colall = (int*)  (ws + off); off += (size_t)3 * N_EDGES * 4;        // 7.2 MB
    int*   blksum = (int*)  (ws + off); off += (size_t)512 * 4;
    unsigned short* wt  = (unsigned short*)(ws + off); off += (size_t)2 * 2 * 128 * 256 * 2; // 256 KB
    unsigned short* lbf = (unsigned short*)(ws + off); off += (size_t)N_NODES * D_OUTF * 2;  // 25.6 MB

    hipMemsetAsync(deg, 0, (size_t)3 * N_NODES * 4, stream);

    wt_prep<<<dim3(256, 2), 128, 0, stream>>>(Wl, Wr, wt);
    proj_mfma<<<dim3((N_NODES + 63) / 64, 2), 256, 0, stream>>>(
        x, wt, bl, br, attn, lbuf, rbuf, al, ar, lbf);

    dim3 eg((N_EDGES + 255) / 256, 3);
    hist_kernel<<<eg, 256, 0, stream>>>(ei, deg);
    scan_reduce<<<SCAN_NBLK, 256, 0, stream>>>(deg, blksum);
    scan_mid<<<1, 512, 0, stream>>>(blksum);
    scan_final<<<SCAN_NBLK, 256, 0, stream>>>(deg, blksum, rowst, cursor);
    scatter_kernel<<<eg, 256, 0, stream>>>(ei, cursor, colall);

    aggregate_kernel<<<N_NODES / 4, 256, 0, stream>>>(
        lbuf, (const unsigned int*)lbf, rbuf, al, ar, rowst, deg, colall,
        ral, rar, rbias, out);
}

// Round 10
// 424.614 us; speedup vs baseline: 1.2416x; 1.0302x over previous
//
#include <hip/hip_runtime.h>
#include <hip/hip_bf16.h>

#define N_NODES 100000
#define N_EDGES 600000
#define N_REL   3
#define D_INF   256
#define D_OUTF  128

#define SCAN_TOTAL (3 * N_NODES)                 // 300000
#define SCAN_ELEMS 1024                          // elems per block
#define SCAN_NBLK  ((SCAN_TOTAL + SCAN_ELEMS - 1) / SCAN_ELEMS)  // 293

typedef __attribute__((ext_vector_type(8))) short          bf16x8;
typedef __attribute__((ext_vector_type(8))) unsigned short ushort8;
typedef __attribute__((ext_vector_type(4))) float          f32x4;

// main-loop LDS row stride (bf16 elems): 144B rows, 16B aligned, ~2-way bank
#define LPAD 72
// phase-2 (attn-MFMA) LDS row stride: 272B rows
#define LTS  136

__device__ __forceinline__ unsigned short bf16_rne(float v) {
    unsigned int b = __float_as_uint(v);
    b += 0x7FFFu + ((b >> 16) & 1u);
    return (unsigned short)(b >> 16);
}

// ---------------------------------------------------------------------------
// K0: W [256][128] f32  ->  Wt_{hi,lo} [128 cols][256 k] bf16  (per W)
// ---------------------------------------------------------------------------
__global__ __launch_bounds__(128) void wt_prep(
    const float* __restrict__ Wl, const float* __restrict__ Wr,
    unsigned short* __restrict__ wt)
{
    const int k = blockIdx.x;      // 0..255
    const int w = blockIdx.y;      // 0,1
    const int n = threadIdx.x;     // 0..127
    const float v = (w ? Wr : Wl)[(size_t)k * D_OUTF + n];
    const unsigned short h = bf16_rne(v);
    const float fhi = __uint_as_float(((unsigned int)h) << 16);
    const unsigned short g = bf16_rne(v - fhi);
    const size_t base = (size_t)w * 2 * 128 * 256;
    wt[base + (size_t)n * 256 + k]          = h;
    wt[base + 32768 + (size_t)n * 256 + k]  = g;
}

// ---------------------------------------------------------------------------
// K1: projection GEMM via split-bf16 MFMA (C = xhi*Whi + xhi*Wlo + xlo*Whi)
// Fused: al/ar via 12-MFMA attn chain; l output written ONLY as bf16 (lbf);
// r output written f32 (rbuf).
// ---------------------------------------------------------------------------
__global__ __launch_bounds__(256) void proj_mfma(
    const float* __restrict__ x, const unsigned short* __restrict__ wt,
    const float* __restrict__ bl, const float* __restrict__ br,
    const float* __restrict__ attn,
    float* __restrict__ rbuf,
    float* __restrict__ al,   float* __restrict__ ar,
    unsigned short* __restrict__ lbf)
{
    __shared__ unsigned short smem[2 * 64 * LPAD + 2 * 128 * LPAD]; // 27648 us
    unsigned short* xs0 = smem;                  // [2][64][LPAD]
    unsigned short* ws0 = smem + 2 * 64 * LPAD;  // [2][128][LPAD]
    // phase-2 aliases (main tiles dead by then)
    unsigned short* lt0 = smem;                  // [2][64][LTS]
    unsigned short* at0 = smem + 2 * 64 * LTS;   // [2][16][LTS]

    const int tid  = threadIdx.x;
    const int nb   = blockIdx.x * 64;
    const int w    = blockIdx.y;
    const unsigned short* wtw = wt + (size_t)w * 2 * 128 * 256;
    const float* bias = w ? br : bl;

    const int lane = tid & 63;
    const int wv   = tid >> 6;      // wave 0..3
    const int rowf = lane & 15;
    const int kgrp = lane >> 4;     // 0..3

    f32x4 acc[8];
#pragma unroll
    for (int cf = 0; cf < 8; ++cf) acc[cf] = (f32x4){0.f, 0.f, 0.f, 0.f};

    float bv[8];
#pragma unroll
    for (int cf = 0; cf < 8; ++cf) bv[cf] = bias[cf * 16 + rowf];

    for (int kb = 0; kb < D_INF; kb += 64) {
        __syncthreads();
        // ---- stage x tile: thread t -> row t>>2, 16 k's at (t&3)*16
        {
            const int r   = tid >> 2;
            const int seg = tid & 3;
            int rowg = nb + r; if (rowg >= N_NODES) rowg = N_NODES - 1;
            const float* src = x + (size_t)rowg * D_INF + kb + seg * 16;
#pragma unroll
            for (int q2 = 0; q2 < 2; ++q2) {
                const float4 v0 = *reinterpret_cast<const float4*>(src + q2 * 8);
                const float4 v1 = *reinterpret_cast<const float4*>(src + q2 * 8 + 4);
                const float vv[8] = {v0.x, v0.y, v0.z, v0.w, v1.x, v1.y, v1.z, v1.w};
                ushort8 hv, gv;
#pragma unroll
                for (int q = 0; q < 8; ++q) {
                    const unsigned short h = bf16_rne(vv[q]);
                    hv[q] = h;
                    const float fhi = __uint_as_float(((unsigned int)h) << 16);
                    gv[q] = bf16_rne(vv[q] - fhi);
                }
                *reinterpret_cast<ushort8*>(&xs0[0 * 64 * LPAD + r * LPAD + seg * 16 + q2 * 8]) = hv;
                *reinterpret_cast<ushort8*>(&xs0[1 * 64 * LPAD + r * LPAD + seg * 16 + q2 * 8]) = gv;
            }
        }
        // ---- stage W^T tile: thread t -> col n=t>>1, 32 k's at (t&1)*32
        {
            const int n    = tid >> 1;
            const int half = tid & 1;
            const uint4* sh = reinterpret_cast<const uint4*>(wtw + (size_t)n * 256 + kb + half * 32);
            const uint4* sl = reinterpret_cast<const uint4*>(wtw + 32768 + (size_t)n * 256 + kb + half * 32);
            uint4* dh = reinterpret_cast<uint4*>(&ws0[0 * 128 * LPAD + n * LPAD + half * 32]);
            uint4* dl = reinterpret_cast<uint4*>(&ws0[1 * 128 * LPAD + n * LPAD + half * 32]);
#pragma unroll
            for (int q = 0; q < 4; ++q) { dh[q] = sh[q]; dl[q] = sl[q]; }
        }
        __syncthreads();

        // ---- MFMA over the 2 k32-steps of this BK
#pragma unroll
        for (int kk = 0; kk < 2; ++kk) {
            const int ko = kk * 32 + kgrp * 8;
            const bf16x8 ahi = *reinterpret_cast<const bf16x8*>(&xs0[0 * 64 * LPAD + (wv * 16 + rowf) * LPAD + ko]);
            const bf16x8 alo = *reinterpret_cast<const bf16x8*>(&xs0[1 * 64 * LPAD + (wv * 16 + rowf) * LPAD + ko]);
#pragma unroll
            for (int cf = 0; cf < 8; ++cf) {
                const bf16x8 bhi = *reinterpret_cast<const bf16x8*>(&ws0[0 * 128 * LPAD + (cf * 16 + rowf) * LPAD + ko]);
                const bf16x8 blo = *reinterpret_cast<const bf16x8*>(&ws0[1 * 128 * LPAD + (cf * 16 + rowf) * LPAD + ko]);
                acc[cf] = __builtin_amdgcn_mfma_f32_16x16x32_bf16(ahi, bhi, acc[cf], 0, 0, 0);
                acc[cf] = __builtin_amdgcn_mfma_f32_16x16x32_bf16(ahi, blo, acc[cf], 0, 0, 0);
                acc[cf] = __builtin_amdgcn_mfma_f32_16x16x32_bf16(alo, bhi, acc[cf], 0, 0, 0);
            }
        }
    }

    // ==== phase 2: epilogue + fused al/ar ====
    __syncthreads();   // main-tile LDS reads complete; safe to reuse

    // relu output -> split-bf16 l/r tile in LDS (+ f32 store for r only)
#pragma unroll
    for (int cf = 0; cf < 8; ++cf) {
#pragma unroll
        for (int j = 0; j < 4; ++j) {
            const int r    = wv * 16 + kgrp * 4 + j;   // row within tile
            const int node = nb + r;
            const float o  = fmaxf(acc[cf][j] + bv[cf], 0.f);
            if (w == 1 && node < N_NODES)
                rbuf[(size_t)node * D_OUTF + cf * 16 + rowf] = o;
            const unsigned short h = bf16_rne(o);
            const float fhi = __uint_as_float(((unsigned int)h) << 16);
            const unsigned short g = bf16_rne(o - fhi);
            lt0[0 * 64 * LTS + r * LTS + cf * 16 + rowf] = h;
            lt0[1 * 64 * LTS + r * LTS + cf * 16 + rowf] = g;
        }
    }

    // stage attn matrix (sparse band, transposed, split hi/lo)
    {
        const int woff = w ? 32 : 0;
#pragma unroll
        for (int q = 0; q < 8; ++q) {
            const int idx = tid * 8 + q;       // 0..2047
            const int c   = idx >> 4;
            const int o   = idx & 15;
            const int rr  = o >> 2;
            const int hh  = o & 3;
            const float v = (hh == (c >> 5) && o < 12)
                          ? attn[rr * 256 + hh * 64 + woff + (c & 31)] : 0.f;
            const unsigned short h = bf16_rne(v);
            const float fhi = __uint_as_float(((unsigned int)h) << 16);
            const unsigned short g = bf16_rne(v - fhi);
            at0[0 * 16 * LTS + o * LTS + c] = h;
            at0[1 * 16 * LTS + o * LTS + c] = g;
        }
    }
    __syncthreads();

    // 12-MFMA chain: (l hi/lo) x (attn hi/lo), 4 k32 steps over 128 cols
    f32x4 acc2 = (f32x4){0.f, 0.f, 0.f, 0.f};
#pragma unroll
    for (int ks = 0; ks < 4; ++ks) {
        const int ko = ks * 32 + kgrp * 8;
        const bf16x8 ahi = *reinterpret_cast<const bf16x8*>(&lt0[0 * 64 * LTS + (wv * 16 + rowf) * LTS + ko]);
        const bf16x8 alo = *reinterpret_cast<const bf16x8*>(&lt0[1 * 64 * LTS + (wv * 16 + rowf) * LTS + ko]);
        const bf16x8 bhi = *reinterpret_cast<const bf16x8*>(&at0[0 * 16 * LTS + rowf * LTS + ko]);
        const bf16x8 blo = *reinterpret_cast<const bf16x8*>(&at0[1 * 16 * LTS + rowf * LTS + ko]);
        acc2 = __builtin_amdgcn_mfma_f32_16x16x32_bf16(ahi, bhi, acc2, 0, 0, 0);
        acc2 = __builtin_amdgcn_mfma_f32_16x16x32_bf16(ahi, blo, acc2, 0, 0, 0);
        acc2 = __builtin_amdgcn_mfma_f32_16x16x32_bf16(alo, bhi, acc2, 0, 0, 0);
    }
    {
        float* tab = w ? ar : al;
        if (rowf < 12) {
#pragma unroll
            for (int reg = 0; reg < 4; ++reg) {
                const int node = nb + wv * 16 + kgrp * 4 + reg;
                if (node < N_NODES) tab[(size_t)node * 12 + rowf] = acc2[reg];
            }
        }
    }

    // lbf (bf16 l copy) from LDS l-tile, coalesced  (w==0 only)
    if (w == 0) {
#pragma unroll
        for (int q = 0; q < 4; ++q) {
            const int idx = tid + q * 256;     // 0..1023 chunks of 8 us
            const int r   = idx >> 4;
            const int c8  = (idx & 15) * 8;
            const int node = nb + r;
            if (node < N_NODES)
                *reinterpret_cast<ushort8*>(&lbf[(size_t)node * D_OUTF + c8]) =
                    *reinterpret_cast<ushort8*>(&lt0[0 * 64 * LTS + r * LTS + c8]);
        }
    }
}

// ---------------------------------------------------------------------------
// K3: degree histogram (by dst)
// ---------------------------------------------------------------------------
__global__ __launch_bounds__(256) void hist_kernel(const int* __restrict__ ei,
                                                   int* __restrict__ deg)
{
    const int rr = blockIdx.y;
    const int e  = blockIdx.x * 256 + threadIdx.x;
    if (e < N_EDGES) {
        const int dst = ei[(size_t)rr * 2 * N_EDGES + N_EDGES + e];
        atomicAdd(&deg[rr * N_NODES + dst], 1);
    }
}

// ---------------------------------------------------------------------------
// K4a: per-block reduce (1024 elems/block, 256 thr x 4)
// ---------------------------------------------------------------------------
__global__ __launch_bounds__(256) void scan_reduce(const int* __restrict__ deg,
                                                   int* __restrict__ blksum)
{
    __shared__ int ws[4];
    const int tid  = threadIdx.x;
    const int lane = tid & 63;
    const int wid  = tid >> 6;
    const int idx  = blockIdx.x * SCAN_ELEMS + tid * 4;
    int t = 0;
#pragma unroll
    for (int j = 0; j < 4; ++j)
        if (idx + j < SCAN_TOTAL) t += deg[idx + j];
#pragma unroll
    for (int off = 32; off >= 1; off >>= 1) t += __shfl_xor(t, off);
    if (lane == 0) ws[wid] = t;
    __syncthreads();
    if (tid == 0) blksum[blockIdx.x] = ws[0] + ws[1] + ws[2] + ws[3];
}

// ---------------------------------------------------------------------------
// K4b: single-block exclusive scan of the 293 block sums (512 threads)
// ---------------------------------------------------------------------------
__global__ __launch_bounds__(512) void scan_mid(int* __restrict__ blksum)
{
    __shared__ int sh[512];
    const int tid = threadIdx.x;
    const int v = (tid < SCAN_NBLK) ? blksum[tid] : 0;
    sh[tid] = v;
    __syncthreads();
#pragma unroll
    for (int off = 1; off < 512; off <<= 1) {
        const int u = (tid >= off) ? sh[tid - off] : 0;
        __syncthreads();
        sh[tid] += u;
        __syncthreads();
    }
    if (tid < SCAN_NBLK) blksum[tid] = sh[tid] - v;   // exclusive
}

// ---------------------------------------------------------------------------
// K4c: per-block scan + block offset -> rowst, cursor
// ---------------------------------------------------------------------------
__global__ __launch_bounds__(256) void scan_final(const int* __restrict__ deg,
    const int* __restrict__ blkoff, int* __restrict__ rowst,
    int* __restrict__ cursor)
{
    __shared__ int wsum[4];
    __shared__ int wexcl[4];
    const int tid  = threadIdx.x;
    const int lane = tid & 63;
    const int wid  = tid >> 6;
    const int idx  = blockIdx.x * SCAN_ELEMS + tid * 4;

    const int v0 = (idx + 0 < SCAN_TOTAL) ? deg[idx + 0] : 0;
    const int v1 = (idx + 1 < SCAN_TOTAL) ? deg[idx + 1] : 0;
    const int v2 = (idx + 2 < SCAN_TOTAL) ? deg[idx + 2] : 0;
    const int v3 = (idx + 3 < SCAN_TOTAL) ? deg[idx + 3] : 0;
    const int tsum = v0 + v1 + v2 + v3;
    int inc = tsum;
#pragma unroll
    for (int off = 1; off < 64; off <<= 1) {
        const int u = __shfl_up(inc, off);
        if (lane >= off) inc += u;
    }
    if (lane == 63) wsum[wid] = inc;
    __syncthreads();
    if (tid == 0) {
        int s = 0;
#pragma unroll
        for (int i = 0; i < 4; ++i) { const int t2 = wsum[i]; wexcl[i] = s; s += t2; }
    }
    __syncthreads();
    const int start = blkoff[blockIdx.x] + wexcl[wid] + (inc - tsum);
    if (idx + 0 < SCAN_TOTAL) { rowst[idx + 0] = start; cursor[idx + 0] = start; }
    const int s1 = start + v0;
    if (idx + 1 < SCAN_TOTAL) { rowst[idx + 1] = s1; cursor[idx + 1] = s1; }
    const int s2 = s1 + v1;
    if (idx + 2 < SCAN_TOTAL) { rowst[idx + 2] = s2; cursor[idx + 2] = s2; }
    const int s3 = s2 + v2;
    if (idx + 3 < SCAN_TOTAL) { rowst[idx + 3] = s3; cursor[idx + 3] = s3; }
}

// ---------------------------------------------------------------------------
// K5: scatter src ids into CSR buckets
// ---------------------------------------------------------------------------
__global__ __launch_bounds__(256) void scatter_kernel(const int* __restrict__ ei,
    int* __restrict__ cursor, int* __restrict__ colall)
{
    const int rr = blockIdx.y;
    const int e  = blockIdx.x * 256 + threadIdx.x;
    if (e < N_EDGES) {
        const int src = ei[(size_t)rr * 2 * N_EDGES + e];
        const int dst = ei[(size_t)rr * 2 * N_EDGES + N_EDGES + e];
        const int pos = atomicAdd(&cursor[rr * N_NODES + dst], 1);
        colall[pos] = src;
    }
}

// ---------------------------------------------------------------------------
// K6: aggregation v3.  2 nodes per 64-lane wave (32 lanes each, 4 ch/lane).
// Phase A (lane-parallel): lane j loads its edge's src + al (float4, all 4
// heads), computes leaky+exp once.  Phase B (serial i over chunk): broadcast
// src + 4 weights via shfl, select by head, one coalesced uint2 bf16 gather,
// 4 FMAs.  Both halves run in lockstep (cntmax), padding weights with 0.
// ---------------------------------------------------------------------------
__global__ __launch_bounds__(256) void aggregate_kernel(
    const unsigned int* __restrict__ lbf32, const float* __restrict__ rbuf,
    const float* __restrict__ al,   const float* __restrict__ ar,
    const int* __restrict__ rowst,  const int* __restrict__ deg,
    const int* __restrict__ colall,
    const float* __restrict__ rel_attn_l, const float* __restrict__ rel_attn_r,
    const float* __restrict__ rel_bias,   float* __restrict__ out)
{
    const int wv   = threadIdx.x >> 6;
    const int lane = threadIdx.x & 63;
    const int g    = lane >> 5;          // node slot within wave (0/1)
    const int j    = lane & 31;          // lane within half
    const int n    = blockIdx.x * 8 + wv * 2 + g;
    if (n >= N_NODES) return;

    const int h  = j >> 3;               // head 0..3 (8 lanes per head)
    const int c4 = j * 4;                // first of 4 owned channels
    const int gbase = lane & 32;         // shfl base for own half

    float ex[3][4];
    float den[3];
#pragma unroll
    for (int rr = 0; rr < 3; ++rr) {
        den[rr] = 0.f;
#pragma unroll
        for (int c = 0; c < 4; ++c) ex[rr][c] = 0.f;
    }

#pragma unroll
    for (int rr = 0; rr < 3; ++rr) {
        const int start = rowst[rr * N_NODES + n];
        const int cnt   = deg[rr * N_NODES + n];
        const float4 ar4 = *reinterpret_cast<const float4*>(ar + (size_t)n * 12 + rr * 4);
        const int cnt_o  = __shfl(cnt, lane ^ 32);
        const int cntmax = max(cnt, cnt_o);

        for (int base = 0; base < cntmax; base += 32) {
            const int mm = min(32, max(0, cnt - base));        // own half's count
            const int mx = min(32, cntmax - base);             // lockstep bound
            // ---- phase A: per-lane edge weight (4 heads)
            const int srcj = (j < mm) ? colall[start + base + j] : 0;
            const float4 al4 = *reinterpret_cast<const float4*>(al + (size_t)srcj * 12 + rr * 4);
            float t0 = al4.x + ar4.x, t1 = al4.y + ar4.y;
            float t2 = al4.z + ar4.z, t3 = al4.w + ar4.w;
            t0 = fmaxf(t0, 0.2f * t0); t1 = fmaxf(t1, 0.2f * t1);
            t2 = fmaxf(t2, 0.2f * t2); t3 = fmaxf(t3, 0.2f * t3);
            float w0 = __expf(t0), w1 = __expf(t1);
            float w2 = __expf(t2), w3 = __expf(t3);
            if (j >= mm) { w0 = 0.f; w1 = 0.f; w2 = 0.f; w3 = 0.f; }
            // ---- phase B: serial accumulate over chunk edges
#pragma unroll 2
            for (int i = 0; i < mx; ++i) {
                const int sl   = gbase + i;
                const int srcI = __shfl(srcj, sl);
                const float b0 = __shfl(w0, sl);
                const float b1 = __shfl(w1, sl);
                const float b2 = __shfl(w2, sl);
                const float b3 = __shfl(w3, sl);
                const float wsel = (h & 2) ? ((h & 1) ? b3 : b2)
                                           : ((h & 1) ? b1 : b0);
                const uint2 u = *reinterpret_cast<const uint2*>(
                    lbf32 + (size_t)srcI * 64 + j * 2);
                den[rr] += wsel;
                ex[rr][0] = fmaf(wsel, __uint_as_float(u.x << 16),          ex[rr][0]);
                ex[rr][1] = fmaf(wsel, __uint_as_float(u.x & 0xFFFF0000u),  ex[rr][1]);
                ex[rr][2] = fmaf(wsel, __uint_as_float(u.y << 16),          ex[rr][2]);
                ex[rr][3] = fmaf(wsel, __uint_as_float(u.y & 0xFFFF0000u),  ex[rr][3]);
            }
        }
    }

    // normalized relation embeddings + self slot (bf16)
    float e[4][4];
#pragma unroll
    for (int rr = 0; rr < 3; ++rr) {
        const float inv = 1.f / (den[rr] + 1e-16f);
#pragma unroll
        for (int c = 0; c < 4; ++c) e[rr][c] = ex[rr][c] * inv;
    }
    {
        const uint2 u = *reinterpret_cast<const uint2*>(lbf32 + (size_t)n * 64 + j * 2);
        e[3][0] = __uint_as_float(u.x << 16);
        e[3][1] = __uint_as_float(u.x & 0xFFFF0000u);
        e[3][2] = __uint_as_float(u.y << 16);
        e[3][3] = __uint_as_float(u.y & 0xFFFF0000u);
    }

    // relation-level beta attention
    const float4 rv4  = *reinterpret_cast<const float4*>(rbuf + (size_t)n * D_OUTF + c4);
    const float4 ral4 = *reinterpret_cast<const float4*>(rel_attn_l + c4);
    float blc[4];
    blc[0] = fmaxf(rv4.x * ral4.x, 0.f);
    blc[1] = fmaxf(rv4.y * ral4.y, 0.f);
    blc[2] = fmaxf(rv4.z * ral4.z, 0.f);
    blc[3] = fmaxf(rv4.w * ral4.w, 0.f);

    float beta[4];
#pragma unroll
    for (int s = 0; s < 4; ++s) {
        const float4 rar4 = *reinterpret_cast<const float4*>(rel_attn_r + s * D_OUTF + c4);
        float p = 0.f;
        p = fmaf(blc[0], fmaxf(e[s][0] * rar4.x, 0.f), p);
        p = fmaf(blc[1], fmaxf(e[s][1] * rar4.y, 0.f), p);
        p = fmaf(blc[2], fmaxf(e[s][2] * rar4.z, 0.f), p);
        p = fmaf(blc[3], fmaxf(e[s][3] * rar4.w, 0.f), p);
        // reduce over the 8-lane head group
#pragma unroll
        for (int m = 4; m >= 1; m >>= 1) p += __shfl_xor(p, m);
        beta[s] = p + rel_bias[s];
    }

    // softmax over the 4 relation slots (per head)
    const float mx2 = fmaxf(fmaxf(beta[0], beta[1]), fmaxf(beta[2], beta[3]));
    float ssum = 0.f;
#pragma unroll
    for (int s = 0; s < 4; ++s) { beta[s] = __expf(beta[s] - mx2); ssum += beta[s]; }
    const float isum = 1.f / ssum;
    float4 ov;
    float o0 = 0.f, o1 = 0.f, o2 = 0.f, o3 = 0.f;
#pragma unroll
    for (int s = 0; s < 4; ++s) {
        const float b = beta[s] * isum;
        o0 = fmaf(e[s][0], b, o0);
        o1 = fmaf(e[s][1], b, o1);
        o2 = fmaf(e[s][2], b, o2);
        o3 = fmaf(e[s][3], b, o3);
    }
    ov.x = fmaxf(o0, 0.f);
    ov.y = fmaxf(o1, 0.f);
    ov.z = fmaxf(o2, 0.f);
    ov.w = fmaxf(o3, 0.f);
    *reinterpret_cast<float4*>(out + (size_t)n * D_OUTF + c4) = ov;
}

// ---------------------------------------------------------------------------
extern "C" void kernel_launch(void* const* d_in, const int* in_sizes, int n_in,
                              void* d_out, int out_size, void* d_ws, size_t ws_size,
                              hipStream_t stream)
{
    const float* x     = (const float*)d_in[0];
    const int*   ei    = (const int*)  d_in[1];
    const float* Wl    = (const float*)d_in[2];
    const float* bl    = (const float*)d_in[3];
    const float* Wr    = (const float*)d_in[4];
    const float* br    = (const float*)d_in[5];
    const float* attn  = (const float*)d_in[6];
    const float* ral   = (const float*)d_in[7];
    const float* rar   = (const float*)d_in[8];
    const float* rbias = (const float*)d_in[9];
    float* out = (float*)d_out;

    char* ws = (char*)d_ws;
    size_t off = 0;
    float* rbuf   = (float*)(ws + off); off += (size_t)N_NODES * D_OUTF * 4;   // 51.2 MB
    float* al     = (float*)(ws + off); off += (size_t)N_NODES * 12 * 4;       // 4.8 MB
    float* ar     = (float*)(ws + off); off += (size_t)N_NODES * 12 * 4;       // 4.8 MB
    int*   deg    = (int*)  (ws + off); off += (size_t)3 * N_NODES * 4;        // 1.2 MB
    int*   rowst  = (int*)  (ws + off); off += (size_t)3 * N_NODES * 4;        // 1.2 MB
    int*   cursor = (int*)  (ws + off); off += (size_t)3 * N_NODES * 4;        // 1.2 MB
    int*   colall = (int*)  (ws + off); off += (size_t)3 * N_EDGES * 4;        // 7.2 MB
    int*   blksum = (int*)  (ws + off); off += (size_t)512 * 4;
    unsigned short* wt  = (unsigned short*)(ws + off); off += (size_t)2 * 2 * 128 * 256 * 2; // 256 KB
    unsigned short* lbf = (unsigned short*)(ws + off); off += (size_t)N_NODES * D_OUTF * 2;  // 25.6 MB

    hipMemsetAsync(deg, 0, (size_t)3 * N_NODES * 4, stream);

    wt_prep<<<dim3(256, 2), 128, 0, stream>>>(Wl, Wr, wt);
    proj_mfma<<<dim3((N_NODES + 63) / 64, 2), 256, 0, stream>>>(
        x, wt, bl, br, attn, rbuf, al, ar, lbf);

    dim3 eg((N_EDGES + 255) / 256, 3);
    hist_kernel<<<eg, 256, 0, stream>>>(ei, deg);
    scan_reduce<<<SCAN_NBLK, 256, 0, stream>>>(deg, blksum);
    scan_mid<<<1, 512, 0, stream>>>(blksum);
    scan_final<<<SCAN_NBLK, 256, 0, stream>>>(deg, blksum, rowst, cursor);
    scatter_kernel<<<eg, 256, 0, stream>>>(ei, cursor, colall);

    aggregate_kernel<<<(N_NODES + 7) / 8, 256, 0, stream>>>(
        (const unsigned int*)lbf, rbuf, al, ar, rowst, deg, colall,
        ral, rar, rbias, out);
}

// Round 11
// 349.078 us; speedup vs baseline: 1.5102x; 1.2164x over previous
//
#include <hip/hip_runtime.h>
#include <hip/hip_bf16.h>

#define N_NODES 100000
#define N_EDGES 600000
#define N_REL   3
#define D_INF   256
#define D_OUTF  128

#define SCAN_TOTAL (3 * N_NODES)                 // 300000
#define SCAN_ELEMS 1024                          // elems per block
#define SCAN_NBLK  ((SCAN_TOTAL + SCAN_ELEMS - 1) / SCAN_ELEMS)  // 293

#define NPROJ_BLOCKS (((N_NODES + 63) / 64) * 2)        // 3126
#define NSCAT_BLOCKS ((3 * N_EDGES + 255) / 256)        // 7032
#define NTOT_BLOCKS  (NPROJ_BLOCKS + NSCAT_BLOCKS)      // 10158

typedef __attribute__((ext_vector_type(8))) short          bf16x8;
typedef __attribute__((ext_vector_type(8))) unsigned short ushort8;
typedef __attribute__((ext_vector_type(4))) float          f32x4;

// main-loop LDS row stride (bf16 elems): 144B rows, 16B aligned, ~2-way bank
#define LPAD 72
// phase-2 (attn-MFMA) LDS row stride: 272B rows
#define LTS  136

__device__ __forceinline__ unsigned short bf16_rne(float v) {
    unsigned int b = __float_as_uint(v);
    b += 0x7FFFu + ((b >> 16) & 1u);
    return (unsigned short)(b >> 16);
}

// ---------------------------------------------------------------------------
// K0: W [256][128] f32  ->  Wt_{hi,lo} [128 cols][256 k] bf16  (per W)
// ---------------------------------------------------------------------------
__global__ __launch_bounds__(128) void wt_prep(
    const float* __restrict__ Wl, const float* __restrict__ Wr,
    unsigned short* __restrict__ wt)
{
    const int k = blockIdx.x;      // 0..255
    const int w = blockIdx.y;      // 0,1
    const int n = threadIdx.x;     // 0..127
    const float v = (w ? Wr : Wl)[(size_t)k * D_OUTF + n];
    const unsigned short h = bf16_rne(v);
    const float fhi = __uint_as_float(((unsigned int)h) << 16);
    const unsigned short g = bf16_rne(v - fhi);
    const size_t base = (size_t)w * 2 * 128 * 256;
    wt[base + (size_t)n * 256 + k]          = h;
    wt[base + 32768 + (size_t)n * 256 + k]  = g;
}

// ---------------------------------------------------------------------------
// K1 (FUSED): proj GEMM (split-bf16 MFMA, fused al/ar + lbf)  ∥  CSR scatter.
// Block type chosen by evenly-interleaved split so compute-bound proj blocks
// and memory-latency-bound scatter blocks co-reside on CUs and overlap.
// ---------------------------------------------------------------------------
__global__ __launch_bounds__(256) void proj_scatter(
    const float* __restrict__ x, const unsigned short* __restrict__ wt,
    const float* __restrict__ bl, const float* __restrict__ br,
    const float* __restrict__ attn,
    float* __restrict__ rbuf,
    float* __restrict__ al,   float* __restrict__ ar,
    unsigned short* __restrict__ lbf,
    const int* __restrict__ ei, int* __restrict__ cursor,
    int* __restrict__ colall)
{
    __shared__ unsigned short smem[2 * 64 * LPAD + 2 * 128 * LPAD]; // 55296 B

    const int bid = blockIdx.x;
    const unsigned int pb = (unsigned int)(((unsigned long long)bid * NPROJ_BLOCKS) / NTOT_BLOCKS);
    const unsigned int pa = (unsigned int)(((unsigned long long)(bid + 1) * NPROJ_BLOCKS) / NTOT_BLOCKS);

    if (pa == pb) {
        // ================= scatter block =================
        const int sb = bid - (int)pb;                 // 0..NSCAT_BLOCKS-1
        const int ge = sb * 256 + threadIdx.x;        // 0..1.8M-1
        if (ge < 3 * N_EDGES) {
            const int rr = (ge >= 2 * N_EDGES) ? 2 : ((ge >= N_EDGES) ? 1 : 0);
            const int e  = ge - rr * N_EDGES;
            const int src = ei[(size_t)rr * 2 * N_EDGES + e];
            const int dst = ei[(size_t)rr * 2 * N_EDGES + N_EDGES + e];
            const int pos = atomicAdd(&cursor[rr * N_NODES + dst], 1);
            colall[pos] = src;
        }
        return;
    }

    // ================= proj block #pb =================
    unsigned short* xs0 = smem;                  // [2][64][LPAD]
    unsigned short* ws0 = smem + 2 * 64 * LPAD;  // [2][128][LPAD]
    unsigned short* lt0 = smem;                  // phase-2: [2][64][LTS]
    unsigned short* at0 = smem + 2 * 64 * LTS;   // phase-2: [2][16][LTS]

    const int tid  = threadIdx.x;
    const int nb   = (int)(pb >> 1) * 64;
    const int w    = (int)(pb & 1);
    const unsigned short* wtw = wt + (size_t)w * 2 * 128 * 256;
    const float* bias = w ? br : bl;

    const int lane = tid & 63;
    const int wv   = tid >> 6;      // wave 0..3
    const int rowf = lane & 15;
    const int kgrp = lane >> 4;     // 0..3

    f32x4 acc[8];
#pragma unroll
    for (int cf = 0; cf < 8; ++cf) acc[cf] = (f32x4){0.f, 0.f, 0.f, 0.f};

    float bv[8];
#pragma unroll
    for (int cf = 0; cf < 8; ++cf) bv[cf] = bias[cf * 16 + rowf];

    for (int kb = 0; kb < D_INF; kb += 64) {
        __syncthreads();
        // ---- stage x tile: thread t -> row t>>2, 16 k's at (t&3)*16
        {
            const int r   = tid >> 2;
            const int seg = tid & 3;
            int rowg = nb + r; if (rowg >= N_NODES) rowg = N_NODES - 1;
            const float* src = x + (size_t)rowg * D_INF + kb + seg * 16;
#pragma unroll
            for (int q2 = 0; q2 < 2; ++q2) {
                const float4 v0 = *reinterpret_cast<const float4*>(src + q2 * 8);
                const float4 v1 = *reinterpret_cast<const float4*>(src + q2 * 8 + 4);
                const float vv[8] = {v0.x, v0.y, v0.z, v0.w, v1.x, v1.y, v1.z, v1.w};
                ushort8 hv, gv;
#pragma unroll
                for (int q = 0; q < 8; ++q) {
                    const unsigned short h = bf16_rne(vv[q]);
                    hv[q] = h;
                    const float fhi = __uint_as_float(((unsigned int)h) << 16);
                    gv[q] = bf16_rne(vv[q] - fhi);
                }
                *reinterpret_cast<ushort8*>(&xs0[0 * 64 * LPAD + r * LPAD + seg * 16 + q2 * 8]) = hv;
                *reinterpret_cast<ushort8*>(&xs0[1 * 64 * LPAD + r * LPAD + seg * 16 + q2 * 8]) = gv;
            }
        }
        // ---- stage W^T tile: thread t -> col n=t>>1, 32 k's at (t&1)*32
        {
            const int n    = tid >> 1;
            const int half = tid & 1;
            const uint4* sh = reinterpret_cast<const uint4*>(wtw + (size_t)n * 256 + kb + half * 32);
            const uint4* sl = reinterpret_cast<const uint4*>(wtw + 32768 + (size_t)n * 256 + kb + half * 32);
            uint4* dh = reinterpret_cast<uint4*>(&ws0[0 * 128 * LPAD + n * LPAD + half * 32]);
            uint4* dl = reinterpret_cast<uint4*>(&ws0[1 * 128 * LPAD + n * LPAD + half * 32]);
#pragma unroll
            for (int q = 0; q < 4; ++q) { dh[q] = sh[q]; dl[q] = sl[q]; }
        }
        __syncthreads();

        // ---- MFMA over the 2 k32-steps of this BK
#pragma unroll
        for (int kk = 0; kk < 2; ++kk) {
            const int ko = kk * 32 + kgrp * 8;
            const bf16x8 ahi = *reinterpret_cast<const bf16x8*>(&xs0[0 * 64 * LPAD + (wv * 16 + rowf) * LPAD + ko]);
            const bf16x8 alo = *reinterpret_cast<const bf16x8*>(&xs0[1 * 64 * LPAD + (wv * 16 + rowf) * LPAD + ko]);
#pragma unroll
            for (int cf = 0; cf < 8; ++cf) {
                const bf16x8 bhi = *reinterpret_cast<const bf16x8*>(&ws0[0 * 128 * LPAD + (cf * 16 + rowf) * LPAD + ko]);
                const bf16x8 blo = *reinterpret_cast<const bf16x8*>(&ws0[1 * 128 * LPAD + (cf * 16 + rowf) * LPAD + ko]);
                acc[cf] = __builtin_amdgcn_mfma_f32_16x16x32_bf16(ahi, bhi, acc[cf], 0, 0, 0);
                acc[cf] = __builtin_amdgcn_mfma_f32_16x16x32_bf16(ahi, blo, acc[cf], 0, 0, 0);
                acc[cf] = __builtin_amdgcn_mfma_f32_16x16x32_bf16(alo, bhi, acc[cf], 0, 0, 0);
            }
        }
    }

    // ==== phase 2: epilogue + fused al/ar ====
    __syncthreads();   // main-tile LDS reads complete; safe to reuse

    // relu output -> split-bf16 tile in LDS (+ f32 store for r only)
#pragma unroll
    for (int cf = 0; cf < 8; ++cf) {
#pragma unroll
        for (int j = 0; j < 4; ++j) {
            const int r    = wv * 16 + kgrp * 4 + j;   // row within tile
            const int node = nb + r;
            const float o  = fmaxf(acc[cf][j] + bv[cf], 0.f);
            if (w == 1 && node < N_NODES)
                rbuf[(size_t)node * D_OUTF + cf * 16 + rowf] = o;
            const unsigned short h = bf16_rne(o);
            const float fhi = __uint_as_float(((unsigned int)h) << 16);
            const unsigned short g = bf16_rne(o - fhi);
            lt0[0 * 64 * LTS + r * LTS + cf * 16 + rowf] = h;
            lt0[1 * 64 * LTS + r * LTS + cf * 16 + rowf] = g;
        }
    }

    // stage attn matrix (sparse band, transposed, split hi/lo)
    {
        const int woff = w ? 32 : 0;
#pragma unroll
        for (int q = 0; q < 8; ++q) {
            const int idx = tid * 8 + q;       // 0..2047
            const int c   = idx >> 4;
            const int o   = idx & 15;
            const int rr  = o >> 2;
            const int hh  = o & 3;
            const float v = (hh == (c >> 5) && o < 12)
                          ? attn[rr * 256 + hh * 64 + woff + (c & 31)] : 0.f;
            const unsigned short h = bf16_rne(v);
            const float fhi = __uint_as_float(((unsigned int)h) << 16);
            const unsigned short g = bf16_rne(v - fhi);
            at0[0 * 16 * LTS + o * LTS + c] = h;
            at0[1 * 16 * LTS + o * LTS + c] = g;
        }
    }
    __syncthreads();

    // 12-MFMA chain: (l hi/lo) x (attn hi/lo), 4 k32 steps over 128 cols
    f32x4 acc2 = (f32x4){0.f, 0.f, 0.f, 0.f};
#pragma unroll
    for (int ks = 0; ks < 4; ++ks) {
        const int ko = ks * 32 + kgrp * 8;
        const bf16x8 ahi = *reinterpret_cast<const bf16x8*>(&lt0[0 * 64 * LTS + (wv * 16 + rowf) * LTS + ko]);
        const bf16x8 alo = *reinterpret_cast<const bf16x8*>(&lt0[1 * 64 * LTS + (wv * 16 + rowf) * LTS + ko]);
        const bf16x8 bhi = *reinterpret_cast<const bf16x8*>(&at0[0 * 16 * LTS + rowf * LTS + ko]);
        const bf16x8 blo = *reinterpret_cast<const bf16x8*>(&at0[1 * 16 * LTS + rowf * LTS + ko]);
        acc2 = __builtin_amdgcn_mfma_f32_16x16x32_bf16(ahi, bhi, acc2, 0, 0, 0);
        acc2 = __builtin_amdgcn_mfma_f32_16x16x32_bf16(ahi, blo, acc2, 0, 0, 0);
        acc2 = __builtin_amdgcn_mfma_f32_16x16x32_bf16(alo, bhi, acc2, 0, 0, 0);
    }
    {
        float* tab = w ? ar : al;
        if (rowf < 12) {
#pragma unroll
            for (int reg = 0; reg < 4; ++reg) {
                const int node = nb + wv * 16 + kgrp * 4 + reg;
                if (node < N_NODES) tab[(size_t)node * 12 + rowf] = acc2[reg];
            }
        }
    }

    // lbf (bf16 l copy) from LDS l-tile, coalesced  (w==0 only)
    if (w == 0) {
#pragma unroll
        for (int q = 0; q < 4; ++q) {
            const int idx = tid + q * 256;     // 0..1023 chunks of 8 us
            const int r   = idx >> 4;
            const int c8  = (idx & 15) * 8;
            const int node = nb + r;
            if (node < N_NODES)
                *reinterpret_cast<ushort8*>(&lbf[(size_t)node * D_OUTF + c8]) =
                    *reinterpret_cast<ushort8*>(&lt0[0 * 64 * LTS + r * LTS + c8]);
        }
    }
}

// ---------------------------------------------------------------------------
// K3: degree histogram (by dst)
// ---------------------------------------------------------------------------
__global__ __launch_bounds__(256) void hist_kernel(const int* __restrict__ ei,
                                                   int* __restrict__ deg)
{
    const int rr = blockIdx.y;
    const int e  = blockIdx.x * 256 + threadIdx.x;
    if (e < N_EDGES) {
        const int dst = ei[(size_t)rr * 2 * N_EDGES + N_EDGES + e];
        atomicAdd(&deg[rr * N_NODES + dst], 1);
    }
}

// ---------------------------------------------------------------------------
// K4a: per-block reduce (1024 elems/block, 256 thr x 4)
// ---------------------------------------------------------------------------
__global__ __launch_bounds__(256) void scan_reduce(const int* __restrict__ deg,
                                                   int* __restrict__ blksum)
{
    __shared__ int ws[4];
    const int tid  = threadIdx.x;
    const int lane = tid & 63;
    const int wid  = tid >> 6;
    const int idx  = blockIdx.x * SCAN_ELEMS + tid * 4;
    int t = 0;
#pragma unroll
    for (int j = 0; j < 4; ++j)
        if (idx + j < SCAN_TOTAL) t += deg[idx + j];
#pragma unroll
    for (int off = 32; off >= 1; off >>= 1) t += __shfl_xor(t, off);
    if (lane == 0) ws[wid] = t;
    __syncthreads();
    if (tid == 0) blksum[blockIdx.x] = ws[0] + ws[1] + ws[2] + ws[3];
}

// ---------------------------------------------------------------------------
// K4b: single-block exclusive scan of the 293 block sums (512 threads)
// ---------------------------------------------------------------------------
__global__ __launch_bounds__(512) void scan_mid(int* __restrict__ blksum)
{
    __shared__ int sh[512];
    const int tid = threadIdx.x;
    const int v = (tid < SCAN_NBLK) ? blksum[tid] : 0;
    sh[tid] = v;
    __syncthreads();
#pragma unroll
    for (int off = 1; off < 512; off <<= 1) {
        const int u = (tid >= off) ? sh[tid - off] : 0;
        __syncthreads();
        sh[tid] += u;
        __syncthreads();
    }
    if (tid < SCAN_NBLK) blksum[tid] = sh[tid] - v;   // exclusive
}

// ---------------------------------------------------------------------------
// K4c: per-block scan + block offset -> rowst, cursor
// ---------------------------------------------------------------------------
__global__ __launch_bounds__(256) void scan_final(const int* __restrict__ deg,
    const int* __restrict__ blkoff, int* __restrict__ rowst,
    int* __restrict__ cursor)
{
    __shared__ int wsum[4];
    __shared__ int wexcl[4];
    const int tid  = threadIdx.x;
    const int lane = tid & 63;
    const int wid  = tid >> 6;
    const int idx  = blockIdx.x * SCAN_ELEMS + tid * 4;

    const int v0 = (idx + 0 < SCAN_TOTAL) ? deg[idx + 0] : 0;
    const int v1 = (idx + 1 < SCAN_TOTAL) ? deg[idx + 1] : 0;
    const int v2 = (idx + 2 < SCAN_TOTAL) ? deg[idx + 2] : 0;
    const int v3 = (idx + 3 < SCAN_TOTAL) ? deg[idx + 3] : 0;
    const int tsum = v0 + v1 + v2 + v3;
    int inc = tsum;
#pragma unroll
    for (int off = 1; off < 64; off <<= 1) {
        const int u = __shfl_up(inc, off);
        if (lane >= off) inc += u;
    }
    if (lane == 63) wsum[wid] = inc;
    __syncthreads();
    if (tid == 0) {
        int s = 0;
#pragma unroll
        for (int i = 0; i < 4; ++i) { const int t2 = wsum[i]; wexcl[i] = s; s += t2; }
    }
    __syncthreads();
    const int start = blkoff[blockIdx.x] + wexcl[wid] + (inc - tsum);
    if (idx + 0 < SCAN_TOTAL) { rowst[idx + 0] = start; cursor[idx + 0] = start; }
    const int s1 = start + v0;
    if (idx + 1 < SCAN_TOTAL) { rowst[idx + 1] = s1; cursor[idx + 1] = s1; }
    const int s2 = s1 + v1;
    if (idx + 2 < SCAN_TOTAL) { rowst[idx + 2] = s2; cursor[idx + 2] = s2; }
    const int s3 = s2 + v2;
    if (idx + 3 < SCAN_TOTAL) { rowst[idx + 3] = s3; cursor[idx + 3] = s3; }
}

// ---------------------------------------------------------------------------
// K6: aggregation v3.  2 nodes per 64-lane wave (32 lanes each, 4 ch/lane).
// ---------------------------------------------------------------------------
__global__ __launch_bounds__(256) void aggregate_kernel(
    const unsigned int* __restrict__ lbf32, const float* __restrict__ rbuf,
    const float* __restrict__ al,   const float* __restrict__ ar,
    const int* __restrict__ rowst,  const int* __restrict__ deg,
    const int* __restrict__ colall,
    const float* __restrict__ rel_attn_l, const float* __restrict__ rel_attn_r,
    const float* __restrict__ rel_bias,   float* __restrict__ out)
{
    const int wv   = threadIdx.x >> 6;
    const int lane = threadIdx.x & 63;
    const int g    = lane >> 5;          // node slot within wave (0/1)
    const int j    = lane & 31;          // lane within half
    const int n    = blockIdx.x * 8 + wv * 2 + g;
    if (n >= N_NODES) return;

    const int h  = j >> 3;               // head 0..3 (8 lanes per head)
    const int c4 = j * 4;                // first of 4 owned channels
    const int gbase = lane & 32;         // shfl base for own half

    float ex[3][4];
    float den[3];
#pragma unroll
    for (int rr = 0; rr < 3; ++rr) {
        den[rr] = 0.f;
#pragma unroll
        for (int c = 0; c < 4; ++c) ex[rr][c] = 0.f;
    }

#pragma unroll
    for (int rr = 0; rr < 3; ++rr) {
        const int start = rowst[rr * N_NODES + n];
        const int cnt   = deg[rr * N_NODES + n];
        const float4 ar4 = *reinterpret_cast<const float4*>(ar + (size_t)n * 12 + rr * 4);
        const int cnt_o  = __shfl(cnt, lane ^ 32);
        const int cntmax = max(cnt, cnt_o);

        for (int base = 0; base < cntmax; base += 32) {
            const int mm = min(32, max(0, cnt - base));        // own half's count
            const int mx = min(32, cntmax - base);             // lockstep bound
            // ---- phase A: per-lane edge weight (4 heads)
            const int srcj = (j < mm) ? colall[start + base + j] : 0;
            const float4 al4 = *reinterpret_cast<const float4*>(al + (size_t)srcj * 12 + rr * 4);
            float t0 = al4.x + ar4.x, t1 = al4.y + ar4.y;
            float t2 = al4.z + ar4.z, t3 = al4.w + ar4.w;
            t0 = fmaxf(t0, 0.2f * t0); t1 = fmaxf(t1, 0.2f * t1);
            t2 = fmaxf(t2, 0.2f * t2); t3 = fmaxf(t3, 0.2f * t3);
            float w0 = __expf(t0), w1 = __expf(t1);
            float w2 = __expf(t2), w3 = __expf(t3);
            if (j >= mm) { w0 = 0.f; w1 = 0.f; w2 = 0.f; w3 = 0.f; }
            // ---- phase B: serial accumulate over chunk edges
#pragma unroll 2
            for (int i = 0; i < mx; ++i) {
                const int sl   = gbase + i;
                const int srcI = __shfl(srcj, sl);
                const float b0 = __shfl(w0, sl);
                const float b1 = __shfl(w1, sl);
                const float b2 = __shfl(w2, sl);
                const float b3 = __shfl(w3, sl);
                const float wsel = (h & 2) ? ((h & 1) ? b3 : b2)
                                           : ((h & 1) ? b1 : b0);
                const uint2 u = *reinterpret_cast<const uint2*>(
                    lbf32 + (size_t)srcI * 64 + j * 2);
                den[rr] += wsel;
                ex[rr][0] = fmaf(wsel, __uint_as_float(u.x << 16),          ex[rr][0]);
                ex[rr][1] = fmaf(wsel, __uint_as_float(u.x & 0xFFFF0000u),  ex[rr][1]);
                ex[rr][2] = fmaf(wsel, __uint_as_float(u.y << 16),          ex[rr][2]);
                ex[rr][3] = fmaf(wsel, __uint_as_float(u.y & 0xFFFF0000u),  ex[rr][3]);
            }
        }
    }

    // normalized relation embeddings + self slot (bf16)
    float e[4][4];
#pragma unroll
    for (int rr = 0; rr < 3; ++rr) {
        const float inv = 1.f / (den[rr] + 1e-16f);
#pragma unroll
        for (int c = 0; c < 4; ++c) e[rr][c] = ex[rr][c] * inv;
    }
    {
        const uint2 u = *reinterpret_cast<const uint2*>(lbf32 + (size_t)n * 64 + j * 2);
        e[3][0] = __uint_as_float(u.x << 16);
        e[3][1] = __uint_as_float(u.x & 0xFFFF0000u);
        e[3][2] = __uint_as_float(u.y << 16);
        e[3][3] = __uint_as_float(u.y & 0xFFFF0000u);
    }

    // relation-level beta attention
    const float4 rv4  = *reinterpret_cast<const float4*>(rbuf + (size_t)n * D_OUTF + c4);
    const float4 ral4 = *reinterpret_cast<const float4*>(rel_attn_l + c4);
    float blc[4];
    blc[0] = fmaxf(rv4.x * ral4.x, 0.f);
    blc[1] = fmaxf(rv4.y * ral4.y, 0.f);
    blc[2] = fmaxf(rv4.z * ral4.z, 0.f);
    blc[3] = fmaxf(rv4.w * ral4.w, 0.f);

    float beta[4];
#pragma unroll
    for (int s = 0; s < 4; ++s) {
        const float4 rar4 = *reinterpret_cast<const float4*>(rel_attn_r + s * D_OUTF + c4);
        float p = 0.f;
        p = fmaf(blc[0], fmaxf(e[s][0] * rar4.x, 0.f), p);
        p = fmaf(blc[1], fmaxf(e[s][1] * rar4.y, 0.f), p);
        p = fmaf(blc[2], fmaxf(e[s][2] * rar4.z, 0.f), p);
        p = fmaf(blc[3], fmaxf(e[s][3] * rar4.w, 0.f), p);
        // reduce over the 8-lane head group
#pragma unroll
        for (int m = 4; m >= 1; m >>= 1) p += __shfl_xor(p, m);
        beta[s] = p + rel_bias[s];
    }

    // softmax over the 4 relation slots (per head)
    const float mx2 = fmaxf(fmaxf(beta[0], beta[1]), fmaxf(beta[2], beta[3]));
    float ssum = 0.f;
#pragma unroll
    for (int s = 0; s < 4; ++s) { beta[s] = __expf(beta[s] - mx2); ssum += beta[s]; }
    const float isum = 1.f / ssum;
    float4 ov;
    float o0 = 0.f, o1 = 0.f, o2 = 0.f, o3 = 0.f;
#pragma unroll
    for (int s = 0; s < 4; ++s) {
        const float b = beta[s] * isum;
        o0 = fmaf(e[s][0], b, o0);
        o1 = fmaf(e[s][1], b, o1);
        o2 = fmaf(e[s][2], b, o2);
        o3 = fmaf(e[s][3], b, o3);
    }
    ov.x = fmaxf(o0, 0.f);
    ov.y = fmaxf(o1, 0.f);
    ov.z = fmaxf(o2, 0.f);
    ov.w = fmaxf(o3, 0.f);
    *reinterpret_cast<float4*>(out + (size_t)n * D_OUTF + c4) = ov;
}

// ---------------------------------------------------------------------------
extern "C" void kernel_launch(void* const* d_in, const int* in_sizes, int n_in,
                              void* d_out, int out_size, void* d_ws, size_t ws_size,
                              hipStream_t stream)
{
    const float* x     = (const float*)d_in[0];
    const int*   ei    = (const int*)  d_in[1];
    const float* Wl    = (const float*)d_in[2];
    const float* bl    = (const float*)d_in[3];
    const float* Wr    = (const float*)d_in[4];
    const float* br    = (const float*)d_in[5];
    const float* attn  = (const float*)d_in[6];
    const float* ral   = (const float*)d_in[7];
    const float* rar   = (const float*)d_in[8];
    const float* rbias = (const float*)d_in[9];
    float* out = (float*)d_out;

    char* ws = (char*)d_ws;
    size_t off = 0;
    float* rbuf   = (float*)(ws + off); off += (size_t)N_NODES * D_OUTF * 4;   // 51.2 MB
    float* al     = (float*)(ws + off); off += (size_t)N_NODES * 12 * 4;       // 4.8 MB
    float* ar     = (float*)(ws + off); off += (size_t)N_NODES * 12 * 4;       // 4.8 MB
    int*   deg    = (int*)  (ws + off); off += (size_t)3 * N_NODES * 4;        // 1.2 MB
    int*   rowst  = (int*)  (ws + off); off += (size_t)3 * N_NODES * 4;        // 1.2 MB
    int*   cursor = (int*)  (ws + off); off += (size_t)3 * N_NODES * 4;        // 1.2 MB
    int*   colall = (int*)  (ws + off); off += (size_t)3 * N_EDGES * 4;        // 7.2 MB
    int*   blksum = (int*)  (ws + off); off += (size_t)512 * 4;
    unsigned short* wt  = (unsigned short*)(ws + off); off += (size_t)2 * 2 * 128 * 256 * 2; // 256 KB
    unsigned short* lbf = (unsigned short*)(ws + off); off += (size_t)N_NODES * D_OUTF * 2;  // 25.6 MB

    hipMemsetAsync(deg, 0, (size_t)3 * N_NODES * 4, stream);

    wt_prep<<<dim3(256, 2), 128, 0, stream>>>(Wl, Wr, wt);

    dim3 eg((N_EDGES + 255) / 256, 3);
    hist_kernel<<<eg, 256, 0, stream>>>(ei, deg);
    scan_reduce<<<SCAN_NBLK, 256, 0, stream>>>(deg, blksum);
    scan_mid<<<1, 512, 0, stream>>>(blksum);
    scan_final<<<SCAN_NBLK, 256, 0, stream>>>(deg, blksum, rowst, cursor);

    // fused: proj (compute-bound) overlapped with CSR scatter (latency-bound)
    proj_scatter<<<NTOT_BLOCKS, 256, 0, stream>>>(
        x, wt, bl, br, attn, rbuf, al, ar, lbf, ei, cursor, colall);

    aggregate_kernel<<<(N_NODES + 7) / 8, 256, 0, stream>>>(
        (const unsigned int*)lbf, rbuf, al, ar, rowst, deg, colall,
        ral, rar, rbias, out);
}